// Round 6
// baseline (766.442 us; speedup 1.0000x reference)
//
#include <hip/hip_runtime.h>
#include <math.h>

typedef _Float16 f16x2 __attribute__((ext_vector_type(2)));
typedef _Float16 f16x4 __attribute__((ext_vector_type(4)));
typedef _Float16 f16x8 __attribute__((ext_vector_type(8)));
typedef float f32x4 __attribute__((ext_vector_type(4)));

#define CBITS 10      // 1024 nodes per coarse bucket
#define FCHUNK 4096   // edges per fill block (32KB LDS staging)
// padded weight image: addr(row,col) = 64*row + 8*(row>>1) + col  (f16 units)
// size per 192x64 matrix: 192*64 + 96*8 = 13056 f16 = 26112 B
#define MATSZ 13056
__device__ __forceinline__ int woff(int row) { return 64 * row + 8 * (row >> 1); }

__device__ __forceinline__ float sigmoidf_(float v) {
  return 1.0f / (1.0f + __expf(-v));
}
__device__ __forceinline__ float tanhf_(float v) {
  v = fminf(fmaxf(v, -15.f), 15.f);
  float e = __expf(2.f * v);
  return (e - 1.f) / (e + 1.f);
}
__device__ __forceinline__ float eluf_(float v) { return v > 0.f ? v : (__expf(v) - 1.f); }

// ---------------- fuse conv into GRU input weights, output padded f16 image ----------------
// Wc[j][c] = sum_k conv_w[c][k] * w_ih[j][k]
__global__ __launch_bounds__(256) void fuse_w_kernel(const float* __restrict__ conv_w,
                                                     const float* __restrict__ w_ih,
                                                     _Float16* __restrict__ wcS) {
  const int l = blockIdx.x >> 2;
  const int j0 = (blockIdx.x & 3) * 48;
  const float* W = conv_w + (size_t)l * 4096;   // [c][k]
  const float* wi = w_ih + (size_t)l * 12288;   // [j][k]
  _Float16* out = wcS + (size_t)l * MATSZ;
  __shared__ float sWt[64 * 68];
  __shared__ float sI[48 * 64];
  const int t = threadIdx.x;
  for (int i = t; i < 4096; i += 256) sWt[(i & 63) * 68 + (i >> 6)] = W[i];
  for (int i = t; i < 3072; i += 256) sI[i] = wi[j0 * 64 + i];
  __syncthreads();
#pragma unroll
  for (int r = 0; r < 3; ++r) {
    int u = t + 256 * r;
    int j = u >> 4, cg = (u & 15) * 4;
    float4 a = {0.f, 0.f, 0.f, 0.f};
    for (int k = 0; k < 64; ++k) {
      float4 w = *(const float4*)(sWt + k * 68 + cg);
      float s = sI[j * 64 + k];
      a.x += w.x * s; a.y += w.y * s; a.z += w.z * s; a.w += w.w * s;
    }
    int row = j0 + j;
    f16x4 hv;
    hv[0] = (_Float16)a.x; hv[1] = (_Float16)a.y;
    hv[2] = (_Float16)a.z; hv[3] = (_Float16)a.w;
    *(f16x4*)(out + woff(row) + cg) = hv;
  }
}

// convert whh (f32) to padded f16 image
__global__ __launch_bounds__(256) void whh_prep_kernel(const float* __restrict__ whh,
                                                       _Float16* __restrict__ whhS) {
  int idx = blockIdx.x * 256 + threadIdx.x;  // 5 layers * 192 rows * 16 c4 = 15360
  if (idx >= 15360) return;
  int l = idx / 3072, rem = idx % 3072;
  int r = rem >> 4, c4 = (rem & 15) * 4;
  float4 v = *(const float4*)(whh + (size_t)l * 12288 + r * 64 + c4);
  f16x4 hv;
  hv[0] = (_Float16)v.x; hv[1] = (_Float16)v.y;
  hv[2] = (_Float16)v.z; hv[3] = (_Float16)v.w;
  *(f16x4*)(whhS + (size_t)l * MATSZ + woff(r) + c4) = hv;
}

// ---------------- CSR build: coarse-bucket counting sort ----------------
__global__ __launch_bounds__(256) void bucket_hist_kernel(const int* __restrict__ dst,
                                                          int* __restrict__ bh, int E) {
  __shared__ int h[128];
  const int t = threadIdx.x;
  if (t < 128) h[t] = 0;
  __syncthreads();
  for (int e = blockIdx.x * 256 + t; e < E; e += gridDim.x * 256)
    atomicAdd(&h[dst[e] >> CBITS], 1);
  __syncthreads();
  if (t < 128 && h[t]) atomicAdd(&bh[t * 16], h[t]);  // padded counters: 1 line each
}

__global__ __launch_bounds__(128) void bucket_scan_kernel(int* __restrict__ bh, int nbk,
                                                          int* __restrict__ boffs, int E) {
  __shared__ int s[128];
  const int t = threadIdx.x;
  int v = (t < nbk) ? bh[t * 16] : 0;
  s[t] = v;
  __syncthreads();
  for (int o = 1; o < 128; o <<= 1) {
    int a = (t >= o) ? s[t - o] : 0;
    __syncthreads();
    s[t] += a;
    __syncthreads();
  }
  if (t < nbk) {
    int ex = s[t] - v;
    boffs[t] = ex;
    bh[t * 16] = ex;  // becomes the reservation cursor
  }
  if (t == 0) boffs[nbk] = E;
}

__global__ __launch_bounds__(256) void bucket_fill_kernel(const int* __restrict__ src,
                                                          const int* __restrict__ dst,
                                                          int* __restrict__ bcur,
                                                          unsigned* __restrict__ pairs, int E) {
  __shared__ uint2 staged[FCHUNK];
  __shared__ int h[128], lbase[128], gbase[128], lcur[128];
  const int t = threadIdx.x;
  const int e0 = blockIdx.x * FCHUNK;
  int cnt = E - e0;
  if (cnt > FCHUNK) cnt = FCHUNK;
  if (t < 128) h[t] = 0;
  __syncthreads();
  for (int i = t; i < cnt; i += 256) atomicAdd(&h[dst[e0 + i] >> CBITS], 1);
  __syncthreads();
  if (t < 128) lcur[t] = h[t];
  __syncthreads();
  for (int o = 1; o < 128; o <<= 1) {
    int a = 0;
    if (t < 128 && t >= o) a = lcur[t - o];
    __syncthreads();
    if (t < 128) lcur[t] += a;
    __syncthreads();
  }
  if (t < 128) {
    int ex = lcur[t] - h[t];
    lbase[t] = ex;
    if (h[t]) gbase[t] = atomicAdd(&bcur[t * 16], h[t]);
    lcur[t] = ex;
  }
  __syncthreads();
  for (int i = t; i < cnt; i += 256) {
    int d = dst[e0 + i];
    int b = d >> CBITS;
    int p = atomicAdd(&lcur[b], 1);
    staged[p] = make_uint2((unsigned)src[e0 + i], (unsigned)d);
  }
  __syncthreads();
  // flush: consecutive staged positions within a bucket -> consecutive global positions
  for (int i = t; i < cnt; i += 256) {
    uint2 pr = staged[i];
    int b = (int)(pr.y >> CBITS);
    pairs[gbase[b] + (i - lbase[b])] = (pr.x << CBITS) | (pr.y & ((1u << CBITS) - 1));
  }
}

__global__ __launch_bounds__(256) void csr_build_kernel(const unsigned* __restrict__ pairs,
                                                        const int* __restrict__ boffs,
                                                        int* __restrict__ offs,
                                                        int* __restrict__ srcs, int N, int E) {
  const int b = blockIdx.x, t = threadIdx.x;
  const int nbase = b << CBITS;
  __shared__ int deg[1024];
  __shared__ int ssc[256];
  for (int i = t; i < 1024; i += 256) deg[i] = 0;
  __syncthreads();
  const int beg = boffs[b], end = boffs[b + 1];
  for (int e = beg + t; e < end; e += 256) atomicAdd(&deg[pairs[e] & 1023], 1);
  __syncthreads();
  int d0 = deg[4 * t], d1 = deg[4 * t + 1], d2 = deg[4 * t + 2], d3 = deg[4 * t + 3];
  int s = d0 + d1 + d2 + d3;
  ssc[t] = s;
  __syncthreads();
  for (int o = 1; o < 256; o <<= 1) {
    int a = (t >= o) ? ssc[t - o] : 0;
    __syncthreads();
    ssc[t] += a;
    __syncthreads();
  }
  int base = beg + ssc[t] - s;
  int c0 = base, c1 = c0 + d0, c2 = c1 + d1, c3 = c2 + d2;
  if (nbase + 4 * t + 0 < N) offs[nbase + 4 * t + 0] = c0;
  if (nbase + 4 * t + 1 < N) offs[nbase + 4 * t + 1] = c1;
  if (nbase + 4 * t + 2 < N) offs[nbase + 4 * t + 2] = c2;
  if (nbase + 4 * t + 3 < N) offs[nbase + 4 * t + 3] = c3;
  deg[4 * t] = c0; deg[4 * t + 1] = c1; deg[4 * t + 2] = c2; deg[4 * t + 3] = c3;
  if (b == 0 && t == 0) offs[N] = E;
  __syncthreads();
  for (int e = beg + t; e < end; e += 256) {
    unsigned p = pairs[e];
    int pos = atomicAdd(&deg[p & 1023], 1);
    srcs[pos] = (int)(p >> CBITS);
  }
}

// ---------------- layer-0 algebra: h1 = GRU(0, 0) is one 64-vector ----------------
__global__ __launch_bounds__(64) void h1_kernel(const float* __restrict__ b_ih,
                                                const float* __restrict__ b_hh,
                                                float* __restrict__ h1) {
  int d = threadIdx.x;
  float r = sigmoidf_(b_ih[d] + b_hh[d]);
  float z = sigmoidf_(b_ih[64 + d] + b_hh[64 + d]);
  float n = tanhf_(b_ih[128 + d] + r * b_hh[128 + d]);
  h1[d] = (1.f - z) * n;
}

// broadcast h1 into xh AND write layer-1 aggregate aggh = deg * h1 (merged kernel)
__global__ __launch_bounds__(256) void bcast_kernel(const int* __restrict__ offs,
                                                    const float* __restrict__ h1,
                                                    _Float16* __restrict__ xh,
                                                    _Float16* __restrict__ aggh,
                                                    int N, int units) {
  int idx = blockIdx.x * 256 + threadIdx.x;  // one f16x2 (2 dims) per thread
  if (idx >= units) return;
  int v = idx >> 5, lp = idx & 31;
  float2 hh = *(const float2*)(h1 + lp * 2);
  f16x2 hv;
  hv[0] = (_Float16)hh.x; hv[1] = (_Float16)hh.y;
  *(f16x2*)(xh + (size_t)idx * 2) = hv;
  float dg = (v < N) ? (float)(offs[v + 1] - offs[v]) : 0.f;
  f16x2 av;
  av[0] = (_Float16)(dg * hh.x); av[1] = (_Float16)(dg * hh.y);
  *(f16x2*)(aggh + (size_t)idx * 2) = av;
}

// ---------------- aggregate (f16 gather, 4 edges per load instruction) ----------------
__global__ __launch_bounds__(256) void agg_kernel(const _Float16* __restrict__ xh,
                                                  const int* __restrict__ offs,
                                                  const int* __restrict__ srcs,
                                                  _Float16* __restrict__ aggh, int N) {
  int wave = threadIdx.x >> 6, lane = threadIdx.x & 63;
  int v = blockIdx.x * 4 + wave;
  if (v >= N) return;
  const int beg = offs[v], end = offs[v + 1];
  const int deg = end - beg;
  const int q = lane >> 4;    // which edge of the 4-group this lane serves
  const int lp = lane & 15;   // f16x4 position within the row
  float4 acc = {0.f, 0.f, 0.f, 0.f};
  for (int base = 0; base < deg; base += 64) {
    const int cnt = min(64, deg - base);
    int sidx = srcs[beg + base + lane];  // one vector load: 64 indices (srcs padded +64)
#pragma unroll 2
    for (int e = 0; e < cnt; e += 4) {
      int myedge = e + q;
      int s = __shfl(sidx, myedge);
      f16x4 vv = *(const f16x4*)(xh + (size_t)s * 64 + lp * 4);
      if (myedge < cnt) {
        acc.x += (float)vv[0]; acc.y += (float)vv[1];
        acc.z += (float)vv[2]; acc.w += (float)vv[3];
      }
    }
  }
  acc.x += __shfl_xor(acc.x, 16); acc.y += __shfl_xor(acc.y, 16);
  acc.z += __shfl_xor(acc.z, 16); acc.w += __shfl_xor(acc.w, 16);
  acc.x += __shfl_xor(acc.x, 32); acc.y += __shfl_xor(acc.y, 32);
  acc.z += __shfl_xor(acc.z, 32); acc.w += __shfl_xor(acc.w, 32);
  if (q == 0) {
    f16x4 o;
    o[0] = (_Float16)acc.x; o[1] = (_Float16)acc.y;
    o[2] = (_Float16)acc.z; o[3] = (_Float16)acc.w;
    *(f16x4*)(aggh + (size_t)v * 64 + lp * 4) = o;
  }
}

// ---------------- MFMA GRU: xh = GRUCell(aggh @ Wc^T, xh) ----------------
// f16 padded weight images staged straight into LDS; hold via identity-MFMA.
__global__ __launch_bounds__(256, 3) void gru_kernel(const _Float16* __restrict__ aggh,
                                                     _Float16* __restrict__ xh,
                                                     const _Float16* __restrict__ wcS,
                                                     const _Float16* __restrict__ whhS,
                                                     const float* __restrict__ b_ih,
                                                     const float* __restrict__ b_hh,
                                                     int N, int numTiles) {
  __shared__ _Float16 sW[2 * MATSZ];  // 51 KB
  const int t = threadIdx.x;
  for (int i = t; i < 2 * (MATSZ / 8); i += 256) {  // straight b128 copy
    int mat = (i >= MATSZ / 8);
    int idx = i - mat * (MATSZ / 8);
    *(f16x8*)(sW + mat * MATSZ + idx * 8) =
        *(const f16x8*)((mat ? whhS : wcS) + idx * 8);
  }
  __syncthreads();
  const int wave = t >> 6, lane = t & 63;
  const int q = lane >> 4, c = lane & 15;
  // biases folded into accumulator init
  float bRZ[4], bZZ[4], bIN[4], bHN[4];
#pragma unroll
  for (int dt = 0; dt < 4; ++dt) {
    int d = dt * 16 + c;
    bRZ[dt] = b_ih[d] + b_hh[d];
    bZZ[dt] = b_ih[64 + d] + b_hh[64 + d];
    bIN[dt] = b_ih[128 + d];
    bHN[dt] = b_hh[128 + d];
  }
  // identity B-frags (hold = H @ I in D-layout); only ks = dt>>1 contributes
  f16x8 idf[4];
#pragma unroll
  for (int dt = 0; dt < 4; ++dt) {
    int tgt = (dt & 1) * 16 + c - q * 8;
#pragma unroll
    for (int j = 0; j < 8; ++j) idf[dt][j] = (j == tgt) ? (_Float16)1.0f : (_Float16)0.0f;
  }
  for (int tile = blockIdx.x; tile < numTiles; tile += gridDim.x) {
    const int nb0 = tile * 64 + wave * 16;
    const size_t rowbase = (size_t)(nb0 + c) * 64;
    f16x8 aA[2], aH[2];
#pragma unroll
    for (int ks = 0; ks < 2; ++ks) {
      aA[ks] = *(const f16x8*)(aggh + rowbase + ks * 32 + q * 8);
      aH[ks] = *(const f16x8*)(xh + rowbase + ks * 32 + q * 8);
    }
    f32x4 aR[4], aZ[4], aN[4], aHNa[4], aHO[4];
#pragma unroll
    for (int dt = 0; dt < 4; ++dt) {
      aR[dt] = (f32x4){bRZ[dt], bRZ[dt], bRZ[dt], bRZ[dt]};
      aZ[dt] = (f32x4){bZZ[dt], bZZ[dt], bZZ[dt], bZZ[dt]};
      aN[dt] = (f32x4){bIN[dt], bIN[dt], bIN[dt], bIN[dt]};
      aHNa[dt] = (f32x4){bHN[dt], bHN[dt], bHN[dt], bHN[dt]};
      aHO[dt] = (f32x4){0.f, 0.f, 0.f, 0.f};
    }
#pragma unroll
    for (int ks = 0; ks < 2; ++ks) {
      const int colo = ks * 32 + q * 8;
#pragma unroll
      for (int dt = 0; dt < 4; ++dt) {
        const int r0 = dt * 16 + c;
        f16x8 bWr = *(const f16x8*)(sW + woff(r0) + colo);
        f16x8 bHr = *(const f16x8*)(sW + MATSZ + woff(r0) + colo);
        f16x8 bWz = *(const f16x8*)(sW + woff(64 + r0) + colo);
        f16x8 bHz = *(const f16x8*)(sW + MATSZ + woff(64 + r0) + colo);
        f16x8 bWn = *(const f16x8*)(sW + woff(128 + r0) + colo);
        f16x8 bHn = *(const f16x8*)(sW + MATSZ + woff(128 + r0) + colo);
        aR[dt] = __builtin_amdgcn_mfma_f32_16x16x32_f16(aA[ks], bWr, aR[dt], 0, 0, 0);
        aR[dt] = __builtin_amdgcn_mfma_f32_16x16x32_f16(aH[ks], bHr, aR[dt], 0, 0, 0);
        aZ[dt] = __builtin_amdgcn_mfma_f32_16x16x32_f16(aA[ks], bWz, aZ[dt], 0, 0, 0);
        aZ[dt] = __builtin_amdgcn_mfma_f32_16x16x32_f16(aH[ks], bHz, aZ[dt], 0, 0, 0);
        aN[dt] = __builtin_amdgcn_mfma_f32_16x16x32_f16(aA[ks], bWn, aN[dt], 0, 0, 0);
        aHNa[dt] = __builtin_amdgcn_mfma_f32_16x16x32_f16(aH[ks], bHn, aHNa[dt], 0, 0, 0);
      }
    }
#pragma unroll
    for (int dt = 0; dt < 4; ++dt)
      aHO[dt] = __builtin_amdgcn_mfma_f32_16x16x32_f16(aH[dt >> 1], idf[dt], aHO[dt], 0, 0, 0);
    // epilogue: lane (q,c) holds D[node = nb0 + q*4+r][dim = dt*16+c]
#pragma unroll
    for (int dt = 0; dt < 4; ++dt) {
      int d = dt * 16 + c;
#pragma unroll
      for (int r = 0; r < 4; ++r) {
        int node = nb0 + q * 4 + r;
        if (node < N) {
          float rr = sigmoidf_(aR[dt][r]);
          float zz = sigmoidf_(aZ[dt][r]);
          float nn = tanhf_(aN[dt][r] + rr * aHNa[dt][r]);
          float out = nn + zz * (aHO[dt][r] - nn);
          xh[(size_t)node * 64 + d] = (_Float16)out;
        }
      }
    }
  }
}

// ---------------- pooling (f16 input) ----------------
__global__ __launch_bounds__(256) void pool_kernel(const _Float16* __restrict__ xh,
                                                   const int* __restrict__ batch,
                                                   float* __restrict__ g, int N) {
  int wave = threadIdx.x >> 6, lane = threadIdx.x & 63;
  int n0 = blockIdx.x * 64 + wave * 16;
  if (n0 >= N) return;
  int end = n0 + 16;
  if (end > N) end = N;
  int cur = batch[n0];
  float acc = 0.f;
  for (int n = n0; n < end; ++n) {
    int b = batch[n];
    if (b != cur) {
      atomicAdd(&g[(size_t)cur * 64 + lane], acc);
      acc = 0.f;
      cur = b;
    }
    acc += (float)xh[(size_t)n * 64 + lane];
  }
  atomicAdd(&g[(size_t)cur * 64 + lane], acc);
}

// ---------------- final MLP ----------------
__global__ __launch_bounds__(256) void mlp_kernel(const float* __restrict__ g,
                                                  const float* __restrict__ w1,
                                                  const float* __restrict__ b1,
                                                  const float* __restrict__ w2,
                                                  const float* __restrict__ b2,
                                                  const float* __restrict__ w3,
                                                  const float* __restrict__ b3,
                                                  float* __restrict__ out, int G) {
  __shared__ float sG[64 * 64];
  __shared__ float sH1[64 * 32];
  __shared__ float sH2[64 * 16];
  int t = threadIdx.x;
  for (int i = t; i < G * 64; i += 256) sG[i] = g[i];
  __syncthreads();
  for (int o = t; o < G * 32; o += 256) {
    int gi = o >> 5, i = o & 31;
    float a = b1[i];
    for (int k = 0; k < 64; ++k) a += sG[gi * 64 + k] * w1[i * 64 + k];
    sH1[gi * 32 + i] = eluf_(a);
  }
  __syncthreads();
  for (int o = t; o < G * 16; o += 256) {
    int gi = o >> 4, i = o & 15;
    float a = b2[i];
    for (int k = 0; k < 32; ++k) a += sH1[gi * 32 + k] * w2[i * 32 + k];
    sH2[gi * 16 + i] = eluf_(a);
  }
  __syncthreads();
  for (int o = t; o < G; o += 256) {
    float a = b3[0];
    for (int k = 0; k < 16; ++k) a += sH2[o * 16 + k] * w3[k];
    out[o] = a;
  }
}

extern "C" void kernel_launch(void* const* d_in, const int* in_sizes, int n_in,
                              void* d_out, int out_size, void* d_ws, size_t ws_size,
                              hipStream_t stream) {
  const float* conv_w = (const float*)d_in[0];
  const float* w_ih = (const float*)d_in[1];
  const float* w_hh = (const float*)d_in[2];
  const float* b_ih = (const float*)d_in[3];
  const float* b_hh = (const float*)d_in[4];
  const float* fc1_w = (const float*)d_in[5];
  const float* fc1_b = (const float*)d_in[6];
  const float* fc2_w = (const float*)d_in[7];
  const float* fc2_b = (const float*)d_in[8];
  const float* fc3_w = (const float*)d_in[9];
  const float* fc3_b = (const float*)d_in[10];
  const int* ei = (const int*)d_in[11];
  const int* batch = (const int*)d_in[12];
  const int N = in_sizes[12];
  const int E = in_sizes[11] / 2;
  const int G = out_size;
  const int* src = ei;
  const int* dst = ei + E;
  const int nbk = (N + 1023) >> CBITS;
  const int tiles = (N + 63) / 64;
  const int Npad = tiles * 64;

  char* ws = (char*)d_ws;
  size_t off = 0;
  auto alloc = [&](size_t bytes) -> void* {
    void* p = ws + off;
    off += (bytes + 255) & ~(size_t)255;
    return p;
  };
  _Float16* xh = (_Float16*)alloc((size_t)Npad * 64 * 2);
  _Float16* aggh = (_Float16*)alloc((size_t)Npad * 64 * 2);
  _Float16* wcS = (_Float16*)alloc((size_t)5 * MATSZ * 2);
  _Float16* whhS = (_Float16*)alloc((size_t)5 * MATSZ * 2);
  float* h1 = (float*)alloc(64 * 4);
  float* gbuf = (float*)alloc((size_t)G * 64 * 4);
  int* offs = (int*)alloc((size_t)(N + 1) * 4);
  int* srcs = (int*)alloc((size_t)(E + 64) * 4);
  unsigned* pairs = (unsigned*)alloc((size_t)E * 4);
  int* bh = (int*)alloc(128 * 16 * 4);
  int* boffs = (int*)alloc(129 * 4);

  // --- CSR build ---
  hipMemsetAsync(bh, 0, 128 * 16 * 4, stream);
  bucket_hist_kernel<<<256, 256, 0, stream>>>(dst, bh, E);
  bucket_scan_kernel<<<1, 128, 0, stream>>>(bh, nbk, boffs, E);
  bucket_fill_kernel<<<(E + FCHUNK - 1) / FCHUNK, 256, 0, stream>>>(src, dst, bh, pairs, E);
  csr_build_kernel<<<nbk, 256, 0, stream>>>(pairs, boffs, offs, srcs, N, E);

  // --- weight prep: padded f16 images ---
  fuse_w_kernel<<<20, 256, 0, stream>>>(conv_w, w_ih, wcS);
  whh_prep_kernel<<<60, 256, 0, stream>>>(w_hh, whhS);

  // --- layer 0 (closed form) + layer-1 aggregate (deg * h1), merged ---
  h1_kernel<<<1, 64, 0, stream>>>(b_ih, b_hh, h1);
  bcast_kernel<<<(Npad * 32 + 255) / 256, 256, 0, stream>>>(offs, h1, xh, aggh, N, Npad * 32);

  gru_kernel<<<768, 256, 0, stream>>>(aggh, xh, wcS + MATSZ, whhS + MATSZ,
                                      b_ih + 192, b_hh + 192, N, tiles);
  for (int l = 2; l < 5; ++l) {
    agg_kernel<<<(N + 3) / 4, 256, 0, stream>>>(xh, offs, srcs, aggh, N);
    gru_kernel<<<768, 256, 0, stream>>>(aggh, xh, wcS + (size_t)l * MATSZ,
                                        whhS + (size_t)l * MATSZ, b_ih + (size_t)l * 192,
                                        b_hh + (size_t)l * 192, N, tiles);
  }

  hipMemsetAsync(gbuf, 0, (size_t)G * 64 * 4, stream);
  pool_kernel<<<(N + 63) / 64, 256, 0, stream>>>(xh, batch, gbuf, N);
  mlp_kernel<<<1, 256, 0, stream>>>(gbuf, fc1_w, fc1_b, fc2_w, fc2_b, fc3_w, fc3_b,
                                    (float*)d_out, G);
}

// Round 7
// 475.108 us; speedup vs baseline: 1.6132x; 1.6132x over previous
//
#include <hip/hip_runtime.h>
#include <math.h>

typedef _Float16 f16x2 __attribute__((ext_vector_type(2)));
typedef _Float16 f16x4 __attribute__((ext_vector_type(4)));
typedef _Float16 f16x8 __attribute__((ext_vector_type(8)));
typedef float f32x4 __attribute__((ext_vector_type(4)));

#define CBITS 10      // 1024 nodes per coarse bucket
#define FCHUNK 4096   // edges per fill block (32KB LDS staging)
// padded weight image: addr(row,col) = 64*row + 8*(row>>1) + col  (f16 units)
// size per 192x64 matrix: 192*64 + 96*8 = 13056 f16 = 26112 B
#define MATSZ 13056
__device__ __forceinline__ int woff(int row) { return 64 * row + 8 * (row >> 1); }

__device__ __forceinline__ float sigmoidf_(float v) {
  return 1.0f / (1.0f + __expf(-v));
}
__device__ __forceinline__ float tanhf_(float v) {
  v = fminf(fmaxf(v, -15.f), 15.f);
  float e = __expf(2.f * v);
  return (e - 1.f) / (e + 1.f);
}
__device__ __forceinline__ float eluf_(float v) { return v > 0.f ? v : (__expf(v) - 1.f); }

// ---------------- fuse conv into GRU input weights, output padded f16 image ----------------
// Wc[j][c] = sum_k conv_w[c][k] * w_ih[j][k]
__global__ __launch_bounds__(256) void fuse_w_kernel(const float* __restrict__ conv_w,
                                                     const float* __restrict__ w_ih,
                                                     _Float16* __restrict__ wcS) {
  const int l = blockIdx.x >> 2;
  const int j0 = (blockIdx.x & 3) * 48;
  const float* W = conv_w + (size_t)l * 4096;   // [c][k]
  const float* wi = w_ih + (size_t)l * 12288;   // [j][k]
  _Float16* out = wcS + (size_t)l * MATSZ;
  __shared__ float sWt[64 * 68];
  __shared__ float sI[48 * 64];
  const int t = threadIdx.x;
  for (int i = t; i < 4096; i += 256) sWt[(i & 63) * 68 + (i >> 6)] = W[i];
  for (int i = t; i < 3072; i += 256) sI[i] = wi[j0 * 64 + i];
  __syncthreads();
#pragma unroll
  for (int r = 0; r < 3; ++r) {
    int u = t + 256 * r;
    int j = u >> 4, cg = (u & 15) * 4;
    float4 a = {0.f, 0.f, 0.f, 0.f};
    for (int k = 0; k < 64; ++k) {
      float4 w = *(const float4*)(sWt + k * 68 + cg);
      float s = sI[j * 64 + k];
      a.x += w.x * s; a.y += w.y * s; a.z += w.z * s; a.w += w.w * s;
    }
    int row = j0 + j;
    f16x4 hv;
    hv[0] = (_Float16)a.x; hv[1] = (_Float16)a.y;
    hv[2] = (_Float16)a.z; hv[3] = (_Float16)a.w;
    *(f16x4*)(out + woff(row) + cg) = hv;
  }
}

// convert whh (f32) to padded f16 image
__global__ __launch_bounds__(256) void whh_prep_kernel(const float* __restrict__ whh,
                                                       _Float16* __restrict__ whhS) {
  int idx = blockIdx.x * 256 + threadIdx.x;  // 5 layers * 192 rows * 16 c4 = 15360
  if (idx >= 15360) return;
  int l = idx / 3072, rem = idx % 3072;
  int r = rem >> 4, c4 = (rem & 15) * 4;
  float4 v = *(const float4*)(whh + (size_t)l * 12288 + r * 64 + c4);
  f16x4 hv;
  hv[0] = (_Float16)v.x; hv[1] = (_Float16)v.y;
  hv[2] = (_Float16)v.z; hv[3] = (_Float16)v.w;
  *(f16x4*)(whhS + (size_t)l * MATSZ + woff(r) + c4) = hv;
}

// ---------------- CSR build: coarse-bucket counting sort ----------------
__global__ __launch_bounds__(256) void bucket_hist_kernel(const int* __restrict__ dst,
                                                          int* __restrict__ bh, int E) {
  __shared__ int h[128];
  const int t = threadIdx.x;
  if (t < 128) h[t] = 0;
  __syncthreads();
  for (int e = blockIdx.x * 256 + t; e < E; e += gridDim.x * 256)
    atomicAdd(&h[dst[e] >> CBITS], 1);
  __syncthreads();
  if (t < 128 && h[t]) atomicAdd(&bh[t * 16], h[t]);  // padded counters: 1 line each
}

__global__ __launch_bounds__(128) void bucket_scan_kernel(int* __restrict__ bh, int nbk,
                                                          int* __restrict__ boffs, int E) {
  __shared__ int s[128];
  const int t = threadIdx.x;
  int v = (t < nbk) ? bh[t * 16] : 0;
  s[t] = v;
  __syncthreads();
  for (int o = 1; o < 128; o <<= 1) {
    int a = (t >= o) ? s[t - o] : 0;
    __syncthreads();
    s[t] += a;
    __syncthreads();
  }
  if (t < nbk) {
    int ex = s[t] - v;
    boffs[t] = ex;
    bh[t * 16] = ex;  // becomes the reservation cursor
  }
  if (t == 0) boffs[nbk] = E;
}

__global__ __launch_bounds__(256) void bucket_fill_kernel(const int* __restrict__ src,
                                                          const int* __restrict__ dst,
                                                          int* __restrict__ bcur,
                                                          unsigned* __restrict__ pairs, int E) {
  __shared__ uint2 staged[FCHUNK];
  __shared__ int h[128], lbase[128], gbase[128], lcur[128];
  const int t = threadIdx.x;
  const int e0 = blockIdx.x * FCHUNK;
  int cnt = E - e0;
  if (cnt > FCHUNK) cnt = FCHUNK;
  if (t < 128) h[t] = 0;
  __syncthreads();
  for (int i = t; i < cnt; i += 256) atomicAdd(&h[dst[e0 + i] >> CBITS], 1);
  __syncthreads();
  if (t < 128) lcur[t] = h[t];
  __syncthreads();
  for (int o = 1; o < 128; o <<= 1) {
    int a = 0;
    if (t < 128 && t >= o) a = lcur[t - o];
    __syncthreads();
    if (t < 128) lcur[t] += a;
    __syncthreads();
  }
  if (t < 128) {
    int ex = lcur[t] - h[t];
    lbase[t] = ex;
    if (h[t]) gbase[t] = atomicAdd(&bcur[t * 16], h[t]);
    lcur[t] = ex;
  }
  __syncthreads();
  for (int i = t; i < cnt; i += 256) {
    int d = dst[e0 + i];
    int b = d >> CBITS;
    int p = atomicAdd(&lcur[b], 1);
    staged[p] = make_uint2((unsigned)src[e0 + i], (unsigned)d);
  }
  __syncthreads();
  // flush: consecutive staged positions within a bucket -> consecutive global positions
  for (int i = t; i < cnt; i += 256) {
    uint2 pr = staged[i];
    int b = (int)(pr.y >> CBITS);
    pairs[gbase[b] + (i - lbase[b])] = (pr.x << CBITS) | (pr.y & ((1u << CBITS) - 1));
  }
}

__global__ __launch_bounds__(256) void csr_build_kernel(const unsigned* __restrict__ pairs,
                                                        const int* __restrict__ boffs,
                                                        int* __restrict__ offs,
                                                        int* __restrict__ srcs, int N, int E) {
  const int b = blockIdx.x, t = threadIdx.x;
  const int nbase = b << CBITS;
  __shared__ int deg[1024];
  __shared__ int ssc[256];
  for (int i = t; i < 1024; i += 256) deg[i] = 0;
  __syncthreads();
  const int beg = boffs[b], end = boffs[b + 1];
  for (int e = beg + t; e < end; e += 256) atomicAdd(&deg[pairs[e] & 1023], 1);
  __syncthreads();
  int d0 = deg[4 * t], d1 = deg[4 * t + 1], d2 = deg[4 * t + 2], d3 = deg[4 * t + 3];
  int s = d0 + d1 + d2 + d3;
  ssc[t] = s;
  __syncthreads();
  for (int o = 1; o < 256; o <<= 1) {
    int a = (t >= o) ? ssc[t - o] : 0;
    __syncthreads();
    ssc[t] += a;
    __syncthreads();
  }
  int base = beg + ssc[t] - s;
  int c0 = base, c1 = c0 + d0, c2 = c1 + d1, c3 = c2 + d2;
  if (nbase + 4 * t + 0 < N) offs[nbase + 4 * t + 0] = c0;
  if (nbase + 4 * t + 1 < N) offs[nbase + 4 * t + 1] = c1;
  if (nbase + 4 * t + 2 < N) offs[nbase + 4 * t + 2] = c2;
  if (nbase + 4 * t + 3 < N) offs[nbase + 4 * t + 3] = c3;
  deg[4 * t] = c0; deg[4 * t + 1] = c1; deg[4 * t + 2] = c2; deg[4 * t + 3] = c3;
  if (b == 0 && t == 0) offs[N] = E;
  __syncthreads();
  for (int e = beg + t; e < end; e += 256) {
    unsigned p = pairs[e];
    int pos = atomicAdd(&deg[p & 1023], 1);
    srcs[pos] = (int)(p >> CBITS);
  }
}

// ---------------- layer-0 algebra: h1 = GRU(0, 0) is one 64-vector ----------------
__global__ __launch_bounds__(64) void h1_kernel(const float* __restrict__ b_ih,
                                                const float* __restrict__ b_hh,
                                                float* __restrict__ h1) {
  int d = threadIdx.x;
  float r = sigmoidf_(b_ih[d] + b_hh[d]);
  float z = sigmoidf_(b_ih[64 + d] + b_hh[64 + d]);
  float n = tanhf_(b_ih[128 + d] + r * b_hh[128 + d]);
  h1[d] = (1.f - z) * n;
}

// broadcast h1 into xh AND write layer-1 aggregate aggh = deg * h1 (merged kernel)
__global__ __launch_bounds__(256) void bcast_kernel(const int* __restrict__ offs,
                                                    const float* __restrict__ h1,
                                                    _Float16* __restrict__ xh,
                                                    _Float16* __restrict__ aggh,
                                                    int N, int units) {
  int idx = blockIdx.x * 256 + threadIdx.x;  // one f16x2 (2 dims) per thread
  if (idx >= units) return;
  int v = idx >> 5, lp = idx & 31;
  float2 hh = *(const float2*)(h1 + lp * 2);
  f16x2 hv;
  hv[0] = (_Float16)hh.x; hv[1] = (_Float16)hh.y;
  *(f16x2*)(xh + (size_t)idx * 2) = hv;
  float dg = (v < N) ? (float)(offs[v + 1] - offs[v]) : 0.f;
  f16x2 av;
  av[0] = (_Float16)(dg * hh.x); av[1] = (_Float16)(dg * hh.y);
  *(f16x2*)(aggh + (size_t)idx * 2) = av;
}

// ---------------- aggregate (f16 gather, 4 edges per load instruction) ----------------
__global__ __launch_bounds__(256) void agg_kernel(const _Float16* __restrict__ xh,
                                                  const int* __restrict__ offs,
                                                  const int* __restrict__ srcs,
                                                  _Float16* __restrict__ aggh, int N) {
  int wave = threadIdx.x >> 6, lane = threadIdx.x & 63;
  int v = blockIdx.x * 4 + wave;
  if (v >= N) return;
  const int beg = offs[v], end = offs[v + 1];
  const int deg = end - beg;
  const int q = lane >> 4;    // which edge of the 4-group this lane serves
  const int lp = lane & 15;   // f16x4 position within the row
  float4 acc = {0.f, 0.f, 0.f, 0.f};
  for (int base = 0; base < deg; base += 64) {
    const int cnt = min(64, deg - base);
    int sidx = srcs[beg + base + lane];  // one vector load: 64 indices (srcs padded +64)
#pragma unroll 2
    for (int e = 0; e < cnt; e += 4) {
      int myedge = e + q;
      int s = __shfl(sidx, myedge);
      f16x4 vv = *(const f16x4*)(xh + (size_t)s * 64 + lp * 4);
      if (myedge < cnt) {
        acc.x += (float)vv[0]; acc.y += (float)vv[1];
        acc.z += (float)vv[2]; acc.w += (float)vv[3];
      }
    }
  }
  acc.x += __shfl_xor(acc.x, 16); acc.y += __shfl_xor(acc.y, 16);
  acc.z += __shfl_xor(acc.z, 16); acc.w += __shfl_xor(acc.w, 16);
  acc.x += __shfl_xor(acc.x, 32); acc.y += __shfl_xor(acc.y, 32);
  acc.z += __shfl_xor(acc.z, 32); acc.w += __shfl_xor(acc.w, 32);
  if (q == 0) {
    f16x4 o;
    o[0] = (_Float16)acc.x; o[1] = (_Float16)acc.y;
    o[2] = (_Float16)acc.z; o[3] = (_Float16)acc.w;
    *(f16x4*)(aggh + (size_t)v * 64 + lp * 4) = o;
  }
}

// ---------------- MFMA GRU: xh = GRUCell(aggh @ Wc^T, xh) ----------------
// f16 padded weight images staged straight into LDS; hold via identity-MFMA.
// NOTE: no min-occupancy forcing — (256,3) in round 6 capped the unified VGPR/AGPR
// budget at ~170 and spilled ~300 MB/dispatch to scratch (FETCH~=WRITE~=180MB).
__global__ __launch_bounds__(256) void gru_kernel(const _Float16* __restrict__ aggh,
                                                  _Float16* __restrict__ xh,
                                                  const _Float16* __restrict__ wcS,
                                                  const _Float16* __restrict__ whhS,
                                                  const float* __restrict__ b_ih,
                                                  const float* __restrict__ b_hh,
                                                  int N, int numTiles) {
  __shared__ _Float16 sW[2 * MATSZ];  // 51 KB
  const int t = threadIdx.x;
  for (int i = t; i < 2 * (MATSZ / 8); i += 256) {  // straight b128 copy
    int mat = (i >= MATSZ / 8);
    int idx = i - mat * (MATSZ / 8);
    *(f16x8*)(sW + mat * MATSZ + idx * 8) =
        *(const f16x8*)((mat ? whhS : wcS) + idx * 8);
  }
  __syncthreads();
  const int wave = t >> 6, lane = t & 63;
  const int q = lane >> 4, c = lane & 15;
  // biases folded into accumulator init
  float bRZ[4], bZZ[4], bIN[4], bHN[4];
#pragma unroll
  for (int dt = 0; dt < 4; ++dt) {
    int d = dt * 16 + c;
    bRZ[dt] = b_ih[d] + b_hh[d];
    bZZ[dt] = b_ih[64 + d] + b_hh[64 + d];
    bIN[dt] = b_ih[128 + d];
    bHN[dt] = b_hh[128 + d];
  }
  // identity B-frags (hold = H @ I in D-layout); only ks = dt>>1 contributes
  f16x8 idf[4];
#pragma unroll
  for (int dt = 0; dt < 4; ++dt) {
    int tgt = (dt & 1) * 16 + c - q * 8;
#pragma unroll
    for (int j = 0; j < 8; ++j) idf[dt][j] = (j == tgt) ? (_Float16)1.0f : (_Float16)0.0f;
  }
  for (int tile = blockIdx.x; tile < numTiles; tile += gridDim.x) {
    const int nb0 = tile * 64 + wave * 16;
    const size_t rowbase = (size_t)(nb0 + c) * 64;
    f16x8 aA[2], aH[2];
#pragma unroll
    for (int ks = 0; ks < 2; ++ks) {
      aA[ks] = *(const f16x8*)(aggh + rowbase + ks * 32 + q * 8);
      aH[ks] = *(const f16x8*)(xh + rowbase + ks * 32 + q * 8);
    }
    f32x4 aR[4], aZ[4], aN[4], aHNa[4], aHO[4];
#pragma unroll
    for (int dt = 0; dt < 4; ++dt) {
      aR[dt] = (f32x4){bRZ[dt], bRZ[dt], bRZ[dt], bRZ[dt]};
      aZ[dt] = (f32x4){bZZ[dt], bZZ[dt], bZZ[dt], bZZ[dt]};
      aN[dt] = (f32x4){bIN[dt], bIN[dt], bIN[dt], bIN[dt]};
      aHNa[dt] = (f32x4){bHN[dt], bHN[dt], bHN[dt], bHN[dt]};
      aHO[dt] = (f32x4){0.f, 0.f, 0.f, 0.f};
    }
#pragma unroll
    for (int ks = 0; ks < 2; ++ks) {
      const int colo = ks * 32 + q * 8;
#pragma unroll
      for (int dt = 0; dt < 4; ++dt) {
        const int r0 = dt * 16 + c;
        f16x8 bWr = *(const f16x8*)(sW + woff(r0) + colo);
        f16x8 bHr = *(const f16x8*)(sW + MATSZ + woff(r0) + colo);
        f16x8 bWz = *(const f16x8*)(sW + woff(64 + r0) + colo);
        f16x8 bHz = *(const f16x8*)(sW + MATSZ + woff(64 + r0) + colo);
        f16x8 bWn = *(const f16x8*)(sW + woff(128 + r0) + colo);
        f16x8 bHn = *(const f16x8*)(sW + MATSZ + woff(128 + r0) + colo);
        aR[dt] = __builtin_amdgcn_mfma_f32_16x16x32_f16(aA[ks], bWr, aR[dt], 0, 0, 0);
        aR[dt] = __builtin_amdgcn_mfma_f32_16x16x32_f16(aH[ks], bHr, aR[dt], 0, 0, 0);
        aZ[dt] = __builtin_amdgcn_mfma_f32_16x16x32_f16(aA[ks], bWz, aZ[dt], 0, 0, 0);
        aZ[dt] = __builtin_amdgcn_mfma_f32_16x16x32_f16(aH[ks], bHz, aZ[dt], 0, 0, 0);
        aN[dt] = __builtin_amdgcn_mfma_f32_16x16x32_f16(aA[ks], bWn, aN[dt], 0, 0, 0);
        aHNa[dt] = __builtin_amdgcn_mfma_f32_16x16x32_f16(aH[ks], bHn, aHNa[dt], 0, 0, 0);
      }
    }
#pragma unroll
    for (int dt = 0; dt < 4; ++dt)
      aHO[dt] = __builtin_amdgcn_mfma_f32_16x16x32_f16(aH[dt >> 1], idf[dt], aHO[dt], 0, 0, 0);
    // epilogue: lane (q,c) holds D[node = nb0 + q*4+r][dim = dt*16+c]
#pragma unroll
    for (int dt = 0; dt < 4; ++dt) {
      int d = dt * 16 + c;
#pragma unroll
      for (int r = 0; r < 4; ++r) {
        int node = nb0 + q * 4 + r;
        if (node < N) {
          float rr = sigmoidf_(aR[dt][r]);
          float zz = sigmoidf_(aZ[dt][r]);
          float nn = tanhf_(aN[dt][r] + rr * aHNa[dt][r]);
          float out = nn + zz * (aHO[dt][r] - nn);
          xh[(size_t)node * 64 + d] = (_Float16)out;
        }
      }
    }
  }
}

// ---------------- pooling (f16 input) ----------------
__global__ __launch_bounds__(256) void pool_kernel(const _Float16* __restrict__ xh,
                                                   const int* __restrict__ batch,
                                                   float* __restrict__ g, int N) {
  int wave = threadIdx.x >> 6, lane = threadIdx.x & 63;
  int n0 = blockIdx.x * 64 + wave * 16;
  if (n0 >= N) return;
  int end = n0 + 16;
  if (end > N) end = N;
  int cur = batch[n0];
  float acc = 0.f;
  for (int n = n0; n < end; ++n) {
    int b = batch[n];
    if (b != cur) {
      atomicAdd(&g[(size_t)cur * 64 + lane], acc);
      acc = 0.f;
      cur = b;
    }
    acc += (float)xh[(size_t)n * 64 + lane];
  }
  atomicAdd(&g[(size_t)cur * 64 + lane], acc);
}

// ---------------- final MLP ----------------
__global__ __launch_bounds__(256) void mlp_kernel(const float* __restrict__ g,
                                                  const float* __restrict__ w1,
                                                  const float* __restrict__ b1,
                                                  const float* __restrict__ w2,
                                                  const float* __restrict__ b2,
                                                  const float* __restrict__ w3,
                                                  const float* __restrict__ b3,
                                                  float* __restrict__ out, int G) {
  __shared__ float sG[64 * 64];
  __shared__ float sH1[64 * 32];
  __shared__ float sH2[64 * 16];
  int t = threadIdx.x;
  for (int i = t; i < G * 64; i += 256) sG[i] = g[i];
  __syncthreads();
  for (int o = t; o < G * 32; o += 256) {
    int gi = o >> 5, i = o & 31;
    float a = b1[i];
    for (int k = 0; k < 64; ++k) a += sG[gi * 64 + k] * w1[i * 64 + k];
    sH1[gi * 32 + i] = eluf_(a);
  }
  __syncthreads();
  for (int o = t; o < G * 16; o += 256) {
    int gi = o >> 4, i = o & 15;
    float a = b2[i];
    for (int k = 0; k < 32; ++k) a += sH1[gi * 32 + k] * w2[i * 32 + k];
    sH2[gi * 16 + i] = eluf_(a);
  }
  __syncthreads();
  for (int o = t; o < G; o += 256) {
    float a = b3[0];
    for (int k = 0; k < 16; ++k) a += sH2[o * 16 + k] * w3[k];
    out[o] = a;
  }
}

extern "C" void kernel_launch(void* const* d_in, const int* in_sizes, int n_in,
                              void* d_out, int out_size, void* d_ws, size_t ws_size,
                              hipStream_t stream) {
  const float* conv_w = (const float*)d_in[0];
  const float* w_ih = (const float*)d_in[1];
  const float* w_hh = (const float*)d_in[2];
  const float* b_ih = (const float*)d_in[3];
  const float* b_hh = (const float*)d_in[4];
  const float* fc1_w = (const float*)d_in[5];
  const float* fc1_b = (const float*)d_in[6];
  const float* fc2_w = (const float*)d_in[7];
  const float* fc2_b = (const float*)d_in[8];
  const float* fc3_w = (const float*)d_in[9];
  const float* fc3_b = (const float*)d_in[10];
  const int* ei = (const int*)d_in[11];
  const int* batch = (const int*)d_in[12];
  const int N = in_sizes[12];
  const int E = in_sizes[11] / 2;
  const int G = out_size;
  const int* src = ei;
  const int* dst = ei + E;
  const int nbk = (N + 1023) >> CBITS;
  const int tiles = (N + 63) / 64;
  const int Npad = tiles * 64;

  char* ws = (char*)d_ws;
  size_t off = 0;
  auto alloc = [&](size_t bytes) -> void* {
    void* p = ws + off;
    off += (bytes + 255) & ~(size_t)255;
    return p;
  };
  _Float16* xh = (_Float16*)alloc((size_t)Npad * 64 * 2);
  _Float16* aggh = (_Float16*)alloc((size_t)Npad * 64 * 2);
  _Float16* wcS = (_Float16*)alloc((size_t)5 * MATSZ * 2);
  _Float16* whhS = (_Float16*)alloc((size_t)5 * MATSZ * 2);
  float* h1 = (float*)alloc(64 * 4);
  float* gbuf = (float*)alloc((size_t)G * 64 * 4);
  int* offs = (int*)alloc((size_t)(N + 1) * 4);
  int* srcs = (int*)alloc((size_t)(E + 64) * 4);
  unsigned* pairs = (unsigned*)alloc((size_t)E * 4);
  int* bh = (int*)alloc(128 * 16 * 4);
  int* boffs = (int*)alloc(129 * 4);

  // --- CSR build ---
  hipMemsetAsync(bh, 0, 128 * 16 * 4, stream);
  bucket_hist_kernel<<<256, 256, 0, stream>>>(dst, bh, E);
  bucket_scan_kernel<<<1, 128, 0, stream>>>(bh, nbk, boffs, E);
  bucket_fill_kernel<<<(E + FCHUNK - 1) / FCHUNK, 256, 0, stream>>>(src, dst, bh, pairs, E);
  csr_build_kernel<<<nbk, 256, 0, stream>>>(pairs, boffs, offs, srcs, N, E);

  // --- weight prep: padded f16 images ---
  fuse_w_kernel<<<20, 256, 0, stream>>>(conv_w, w_ih, wcS);
  whh_prep_kernel<<<60, 256, 0, stream>>>(w_hh, whhS);

  // --- layer 0 (closed form) + layer-1 aggregate (deg * h1), merged ---
  h1_kernel<<<1, 64, 0, stream>>>(b_ih, b_hh, h1);
  bcast_kernel<<<(Npad * 32 + 255) / 256, 256, 0, stream>>>(offs, h1, xh, aggh, N, Npad * 32);

  gru_kernel<<<768, 256, 0, stream>>>(aggh, xh, wcS + MATSZ, whhS + MATSZ,
                                      b_ih + 192, b_hh + 192, N, tiles);
  for (int l = 2; l < 5; ++l) {
    agg_kernel<<<(N + 3) / 4, 256, 0, stream>>>(xh, offs, srcs, aggh, N);
    gru_kernel<<<768, 256, 0, stream>>>(aggh, xh, wcS + (size_t)l * MATSZ,
                                        whhS + (size_t)l * MATSZ, b_ih + (size_t)l * 192,
                                        b_hh + (size_t)l * 192, N, tiles);
  }

  hipMemsetAsync(gbuf, 0, (size_t)G * 64 * 4, stream);
  pool_kernel<<<(N + 63) / 64, 256, 0, stream>>>(xh, batch, gbuf, N);
  mlp_kernel<<<1, 256, 0, stream>>>(gbuf, fc1_w, fc1_b, fc2_w, fc2_b, fc3_w, fc3_b,
                                    (float*)d_out, G);
}

// Round 8
// 448.029 us; speedup vs baseline: 1.7107x; 1.0604x over previous
//
#include <hip/hip_runtime.h>
#include <math.h>

typedef _Float16 f16x2 __attribute__((ext_vector_type(2)));
typedef _Float16 f16x4 __attribute__((ext_vector_type(4)));
typedef _Float16 f16x8 __attribute__((ext_vector_type(8)));
typedef float f32x4 __attribute__((ext_vector_type(4)));

#define CBITS 10      // 1024 nodes per coarse bucket
#define FCHUNK 4096   // edges per fill block (32KB LDS staging)
// padded weight image: addr(row,col) = 64*row + 8*(row>>1) + col  (f16 units)
// size per 192x64 matrix: 192*64 + 96*8 = 13056 f16 = 26112 B
#define MATSZ 13056
__device__ __forceinline__ int woff(int row) { return 64 * row + 8 * (row >> 1); }

__device__ __forceinline__ float sigmoidf_(float v) {
  return 1.0f / (1.0f + __expf(-v));
}
__device__ __forceinline__ float tanhf_(float v) {
  v = fminf(fmaxf(v, -15.f), 15.f);
  float e = __expf(2.f * v);
  return (e - 1.f) / (e + 1.f);
}
__device__ __forceinline__ float eluf_(float v) { return v > 0.f ? v : (__expf(v) - 1.f); }

// ---------------- fuse conv into GRU input weights, output padded f16 image ----------------
// Wc[j][c] = sum_k conv_w[c][k] * w_ih[j][k]
__global__ __launch_bounds__(256) void fuse_w_kernel(const float* __restrict__ conv_w,
                                                     const float* __restrict__ w_ih,
                                                     _Float16* __restrict__ wcS) {
  const int l = blockIdx.x >> 2;
  const int j0 = (blockIdx.x & 3) * 48;
  const float* W = conv_w + (size_t)l * 4096;   // [c][k]
  const float* wi = w_ih + (size_t)l * 12288;   // [j][k]
  _Float16* out = wcS + (size_t)l * MATSZ;
  __shared__ float sWt[64 * 68];
  __shared__ float sI[48 * 64];
  const int t = threadIdx.x;
  for (int i = t; i < 4096; i += 256) sWt[(i & 63) * 68 + (i >> 6)] = W[i];
  for (int i = t; i < 3072; i += 256) sI[i] = wi[j0 * 64 + i];
  __syncthreads();
#pragma unroll
  for (int r = 0; r < 3; ++r) {
    int u = t + 256 * r;
    int j = u >> 4, cg = (u & 15) * 4;
    float4 a = {0.f, 0.f, 0.f, 0.f};
    for (int k = 0; k < 64; ++k) {
      float4 w = *(const float4*)(sWt + k * 68 + cg);
      float s = sI[j * 64 + k];
      a.x += w.x * s; a.y += w.y * s; a.z += w.z * s; a.w += w.w * s;
    }
    int row = j0 + j;
    f16x4 hv;
    hv[0] = (_Float16)a.x; hv[1] = (_Float16)a.y;
    hv[2] = (_Float16)a.z; hv[3] = (_Float16)a.w;
    *(f16x4*)(out + woff(row) + cg) = hv;
  }
}

// convert whh (f32) to padded f16 image
__global__ __launch_bounds__(256) void whh_prep_kernel(const float* __restrict__ whh,
                                                       _Float16* __restrict__ whhS) {
  int idx = blockIdx.x * 256 + threadIdx.x;  // 5 layers * 192 rows * 16 c4 = 15360
  if (idx >= 15360) return;
  int l = idx / 3072, rem = idx % 3072;
  int r = rem >> 4, c4 = (rem & 15) * 4;
  float4 v = *(const float4*)(whh + (size_t)l * 12288 + r * 64 + c4);
  f16x4 hv;
  hv[0] = (_Float16)v.x; hv[1] = (_Float16)v.y;
  hv[2] = (_Float16)v.z; hv[3] = (_Float16)v.w;
  *(f16x4*)(whhS + (size_t)l * MATSZ + woff(r) + c4) = hv;
}

// ---------------- CSR build: coarse-bucket counting sort ----------------
__global__ __launch_bounds__(256) void bucket_hist_kernel(const int* __restrict__ dst,
                                                          int* __restrict__ bh, int E) {
  __shared__ int h[128];
  const int t = threadIdx.x;
  if (t < 128) h[t] = 0;
  __syncthreads();
  for (int e = blockIdx.x * 256 + t; e < E; e += gridDim.x * 256)
    atomicAdd(&h[dst[e] >> CBITS], 1);
  __syncthreads();
  if (t < 128 && h[t]) atomicAdd(&bh[t * 16], h[t]);  // padded counters: 1 line each
}

__global__ __launch_bounds__(128) void bucket_scan_kernel(int* __restrict__ bh, int nbk,
                                                          int* __restrict__ boffs, int E) {
  __shared__ int s[128];
  const int t = threadIdx.x;
  int v = (t < nbk) ? bh[t * 16] : 0;
  s[t] = v;
  __syncthreads();
  for (int o = 1; o < 128; o <<= 1) {
    int a = (t >= o) ? s[t - o] : 0;
    __syncthreads();
    s[t] += a;
    __syncthreads();
  }
  if (t < nbk) {
    int ex = s[t] - v;
    boffs[t] = ex;
    bh[t * 16] = ex;  // becomes the reservation cursor
  }
  if (t == 0) boffs[nbk] = E;
}

__global__ __launch_bounds__(256) void bucket_fill_kernel(const int* __restrict__ src,
                                                          const int* __restrict__ dst,
                                                          int* __restrict__ bcur,
                                                          unsigned* __restrict__ pairs, int E) {
  __shared__ uint2 staged[FCHUNK];
  __shared__ int h[128], lbase[128], gbase[128], lcur[128];
  const int t = threadIdx.x;
  const int e0 = blockIdx.x * FCHUNK;
  int cnt = E - e0;
  if (cnt > FCHUNK) cnt = FCHUNK;
  if (t < 128) h[t] = 0;
  __syncthreads();
  for (int i = t; i < cnt; i += 256) atomicAdd(&h[dst[e0 + i] >> CBITS], 1);
  __syncthreads();
  if (t < 128) lcur[t] = h[t];
  __syncthreads();
  for (int o = 1; o < 128; o <<= 1) {
    int a = 0;
    if (t < 128 && t >= o) a = lcur[t - o];
    __syncthreads();
    if (t < 128) lcur[t] += a;
    __syncthreads();
  }
  if (t < 128) {
    int ex = lcur[t] - h[t];
    lbase[t] = ex;
    if (h[t]) gbase[t] = atomicAdd(&bcur[t * 16], h[t]);
    lcur[t] = ex;
  }
  __syncthreads();
  for (int i = t; i < cnt; i += 256) {
    int d = dst[e0 + i];
    int b = d >> CBITS;
    int p = atomicAdd(&lcur[b], 1);
    staged[p] = make_uint2((unsigned)src[e0 + i], (unsigned)d);
  }
  __syncthreads();
  // flush: consecutive staged positions within a bucket -> consecutive global positions
  for (int i = t; i < cnt; i += 256) {
    uint2 pr = staged[i];
    int b = (int)(pr.y >> CBITS);
    pairs[gbase[b] + (i - lbase[b])] = (pr.x << CBITS) | (pr.y & ((1u << CBITS) - 1));
  }
}

__global__ __launch_bounds__(256) void csr_build_kernel(const unsigned* __restrict__ pairs,
                                                        const int* __restrict__ boffs,
                                                        int* __restrict__ offs,
                                                        int* __restrict__ srcs, int N, int E) {
  const int b = blockIdx.x, t = threadIdx.x;
  const int nbase = b << CBITS;
  __shared__ int deg[1024];
  __shared__ int ssc[256];
  for (int i = t; i < 1024; i += 256) deg[i] = 0;
  __syncthreads();
  const int beg = boffs[b], end = boffs[b + 1];
  for (int e = beg + t; e < end; e += 256) atomicAdd(&deg[pairs[e] & 1023], 1);
  __syncthreads();
  int d0 = deg[4 * t], d1 = deg[4 * t + 1], d2 = deg[4 * t + 2], d3 = deg[4 * t + 3];
  int s = d0 + d1 + d2 + d3;
  ssc[t] = s;
  __syncthreads();
  for (int o = 1; o < 256; o <<= 1) {
    int a = (t >= o) ? ssc[t - o] : 0;
    __syncthreads();
    ssc[t] += a;
    __syncthreads();
  }
  int base = beg + ssc[t] - s;
  int c0 = base, c1 = c0 + d0, c2 = c1 + d1, c3 = c2 + d2;
  if (nbase + 4 * t + 0 < N) offs[nbase + 4 * t + 0] = c0;
  if (nbase + 4 * t + 1 < N) offs[nbase + 4 * t + 1] = c1;
  if (nbase + 4 * t + 2 < N) offs[nbase + 4 * t + 2] = c2;
  if (nbase + 4 * t + 3 < N) offs[nbase + 4 * t + 3] = c3;
  deg[4 * t] = c0; deg[4 * t + 1] = c1; deg[4 * t + 2] = c2; deg[4 * t + 3] = c3;
  if (b == 0 && t == 0) offs[N] = E;
  // zero-pad srcs tail: agg reads srcs[beg..beg+deg+63] — pad must be valid node ids
  if (b == 0 && t < 64) srcs[E + t] = 0;
  __syncthreads();
  for (int e = beg + t; e < end; e += 256) {
    unsigned p = pairs[e];
    int pos = atomicAdd(&deg[p & 1023], 1);
    srcs[pos] = (int)(p >> CBITS);
  }
}

// ---------------- layer-0 algebra: h1 = GRU(0, 0) is one 64-vector ----------------
__global__ __launch_bounds__(64) void h1_kernel(const float* __restrict__ b_ih,
                                                const float* __restrict__ b_hh,
                                                float* __restrict__ h1) {
  int d = threadIdx.x;
  float r = sigmoidf_(b_ih[d] + b_hh[d]);
  float z = sigmoidf_(b_ih[64 + d] + b_hh[64 + d]);
  float n = tanhf_(b_ih[128 + d] + r * b_hh[128 + d]);
  h1[d] = (1.f - z) * n;
}

// broadcast h1 into xh AND write layer-1 aggregate aggh = deg * h1 (merged kernel)
__global__ __launch_bounds__(256) void bcast_kernel(const int* __restrict__ offs,
                                                    const float* __restrict__ h1,
                                                    _Float16* __restrict__ xh,
                                                    _Float16* __restrict__ aggh,
                                                    int N, int units) {
  int idx = blockIdx.x * 256 + threadIdx.x;  // one f16x2 (2 dims) per thread
  if (idx >= units) return;
  int v = idx >> 5, lp = idx & 31;
  float2 hh = *(const float2*)(h1 + lp * 2);
  f16x2 hv;
  hv[0] = (_Float16)hh.x; hv[1] = (_Float16)hh.y;
  *(f16x2*)(xh + (size_t)idx * 2) = hv;
  float dg = (v < N) ? (float)(offs[v + 1] - offs[v]) : 0.f;
  f16x2 av;
  av[0] = (_Float16)(dg * hh.x); av[1] = (_Float16)(dg * hh.y);
  *(f16x2*)(aggh + (size_t)idx * 2) = av;
}

// ---------------- aggregate v3: 8 edges per load (f16x8/lane), packed-f16 accumulate ----------------
__global__ __launch_bounds__(256) void agg_kernel(const _Float16* __restrict__ xh,
                                                  const int* __restrict__ offs,
                                                  const int* __restrict__ srcs,
                                                  _Float16* __restrict__ aggh, int N) {
  int wave = threadIdx.x >> 6, lane = threadIdx.x & 63;
  int v = blockIdx.x * 4 + wave;
  if (v >= N) return;
  const int beg = offs[v], end = offs[v + 1];
  const int deg = end - beg;
  const int og = lane >> 3;   // edge slot (0..7) this lane serves
  const int lp = lane & 7;    // f16x8 chunk within the 128B row
  f16x8 acc = {};
  for (int base = 0; base < deg; base += 64) {
    const int cnt = min(64, deg - base);
    int sidx = srcs[beg + base + lane];  // one vector load: 64 indices (srcs zero-padded +64)
    for (int e = 0; e < cnt; e += 8) {
      int me = e + og;
      int s = __shfl(sidx, me);          // pad lanes give s=0: valid row, masked below
      f16x8 vv = *(const f16x8*)(xh + (size_t)s * 64 + lp * 8);
      if (me < cnt) acc += vv;           // 4x v_pk_add_f16
    }
  }
  // reduce across the 8 edge slots (lanes lp, lp+8, ..., lp+56)
#pragma unroll
  for (int off = 8; off < 64; off <<= 1) {
    union { f16x8 h; int i[4]; } a, b;
    a.h = acc;
#pragma unroll
    for (int w = 0; w < 4; ++w) b.i[w] = __shfl_xor(a.i[w], off);
    acc += b.h;
  }
  if (og == 0) *(f16x8*)(aggh + (size_t)v * 64 + lp * 8) = acc;  // 8 lanes x 16B contiguous
}

// ---------------- MFMA GRU: xh = GRUCell(aggh @ Wc^T, xh) ----------------
// f16 padded weight images staged straight into LDS; hold via identity-MFMA.
// NOTE: no min-occupancy forcing — (256,3) in round 6 capped the unified VGPR/AGPR
// budget at ~170 and spilled ~300 MB/dispatch to scratch (FETCH~=WRITE~=180MB).
__global__ __launch_bounds__(256) void gru_kernel(const _Float16* __restrict__ aggh,
                                                  _Float16* __restrict__ xh,
                                                  const _Float16* __restrict__ wcS,
                                                  const _Float16* __restrict__ whhS,
                                                  const float* __restrict__ b_ih,
                                                  const float* __restrict__ b_hh,
                                                  int N, int numTiles) {
  __shared__ _Float16 sW[2 * MATSZ];  // 51 KB
  const int t = threadIdx.x;
  for (int i = t; i < 2 * (MATSZ / 8); i += 256) {  // straight b128 copy
    int mat = (i >= MATSZ / 8);
    int idx = i - mat * (MATSZ / 8);
    *(f16x8*)(sW + mat * MATSZ + idx * 8) =
        *(const f16x8*)((mat ? whhS : wcS) + idx * 8);
  }
  __syncthreads();
  const int wave = t >> 6, lane = t & 63;
  const int q = lane >> 4, c = lane & 15;
  // biases folded into accumulator init
  float bRZ[4], bZZ[4], bIN[4], bHN[4];
#pragma unroll
  for (int dt = 0; dt < 4; ++dt) {
    int d = dt * 16 + c;
    bRZ[dt] = b_ih[d] + b_hh[d];
    bZZ[dt] = b_ih[64 + d] + b_hh[64 + d];
    bIN[dt] = b_ih[128 + d];
    bHN[dt] = b_hh[128 + d];
  }
  // identity B-frags (hold = H @ I in D-layout); only ks = dt>>1 contributes
  f16x8 idf[4];
#pragma unroll
  for (int dt = 0; dt < 4; ++dt) {
    int tgt = (dt & 1) * 16 + c - q * 8;
#pragma unroll
    for (int j = 0; j < 8; ++j) idf[dt][j] = (j == tgt) ? (_Float16)1.0f : (_Float16)0.0f;
  }
  for (int tile = blockIdx.x; tile < numTiles; tile += gridDim.x) {
    const int nb0 = tile * 64 + wave * 16;
    const size_t rowbase = (size_t)(nb0 + c) * 64;
    f16x8 aA[2], aH[2];
#pragma unroll
    for (int ks = 0; ks < 2; ++ks) {
      aA[ks] = *(const f16x8*)(aggh + rowbase + ks * 32 + q * 8);
      aH[ks] = *(const f16x8*)(xh + rowbase + ks * 32 + q * 8);
    }
    f32x4 aR[4], aZ[4], aN[4], aHNa[4], aHO[4];
#pragma unroll
    for (int dt = 0; dt < 4; ++dt) {
      aR[dt] = (f32x4){bRZ[dt], bRZ[dt], bRZ[dt], bRZ[dt]};
      aZ[dt] = (f32x4){bZZ[dt], bZZ[dt], bZZ[dt], bZZ[dt]};
      aN[dt] = (f32x4){bIN[dt], bIN[dt], bIN[dt], bIN[dt]};
      aHNa[dt] = (f32x4){bHN[dt], bHN[dt], bHN[dt], bHN[dt]};
      aHO[dt] = (f32x4){0.f, 0.f, 0.f, 0.f};
    }
#pragma unroll
    for (int ks = 0; ks < 2; ++ks) {
      const int colo = ks * 32 + q * 8;
#pragma unroll
      for (int dt = 0; dt < 4; ++dt) {
        const int r0 = dt * 16 + c;
        f16x8 bWr = *(const f16x8*)(sW + woff(r0) + colo);
        f16x8 bHr = *(const f16x8*)(sW + MATSZ + woff(r0) + colo);
        f16x8 bWz = *(const f16x8*)(sW + woff(64 + r0) + colo);
        f16x8 bHz = *(const f16x8*)(sW + MATSZ + woff(64 + r0) + colo);
        f16x8 bWn = *(const f16x8*)(sW + woff(128 + r0) + colo);
        f16x8 bHn = *(const f16x8*)(sW + MATSZ + woff(128 + r0) + colo);
        aR[dt] = __builtin_amdgcn_mfma_f32_16x16x32_f16(aA[ks], bWr, aR[dt], 0, 0, 0);
        aR[dt] = __builtin_amdgcn_mfma_f32_16x16x32_f16(aH[ks], bHr, aR[dt], 0, 0, 0);
        aZ[dt] = __builtin_amdgcn_mfma_f32_16x16x32_f16(aA[ks], bWz, aZ[dt], 0, 0, 0);
        aZ[dt] = __builtin_amdgcn_mfma_f32_16x16x32_f16(aH[ks], bHz, aZ[dt], 0, 0, 0);
        aN[dt] = __builtin_amdgcn_mfma_f32_16x16x32_f16(aA[ks], bWn, aN[dt], 0, 0, 0);
        aHNa[dt] = __builtin_amdgcn_mfma_f32_16x16x32_f16(aH[ks], bHn, aHNa[dt], 0, 0, 0);
      }
    }
#pragma unroll
    for (int dt = 0; dt < 4; ++dt)
      aHO[dt] = __builtin_amdgcn_mfma_f32_16x16x32_f16(aH[dt >> 1], idf[dt], aHO[dt], 0, 0, 0);
    // epilogue: lane (q,c) holds D[node = nb0 + q*4+r][dim = dt*16+c]
#pragma unroll
    for (int dt = 0; dt < 4; ++dt) {
      int d = dt * 16 + c;
#pragma unroll
      for (int r = 0; r < 4; ++r) {
        int node = nb0 + q * 4 + r;
        if (node < N) {
          float rr = sigmoidf_(aR[dt][r]);
          float zz = sigmoidf_(aZ[dt][r]);
          float nn = tanhf_(aN[dt][r] + rr * aHNa[dt][r]);
          float out = nn + zz * (aHO[dt][r] - nn);
          xh[(size_t)node * 64 + d] = (_Float16)out;
        }
      }
    }
  }
}

// ---------------- pooling (f16 input) ----------------
__global__ __launch_bounds__(256) void pool_kernel(const _Float16* __restrict__ xh,
                                                   const int* __restrict__ batch,
                                                   float* __restrict__ g, int N) {
  int wave = threadIdx.x >> 6, lane = threadIdx.x & 63;
  int n0 = blockIdx.x * 64 + wave * 16;
  if (n0 >= N) return;
  int end = n0 + 16;
  if (end > N) end = N;
  int cur = batch[n0];
  float acc = 0.f;
  for (int n = n0; n < end; ++n) {
    int b = batch[n];
    if (b != cur) {
      atomicAdd(&g[(size_t)cur * 64 + lane], acc);
      acc = 0.f;
      cur = b;
    }
    acc += (float)xh[(size_t)n * 64 + lane];
  }
  atomicAdd(&g[(size_t)cur * 64 + lane], acc);
}

// ---------------- final MLP ----------------
__global__ __launch_bounds__(256) void mlp_kernel(const float* __restrict__ g,
                                                  const float* __restrict__ w1,
                                                  const float* __restrict__ b1,
                                                  const float* __restrict__ w2,
                                                  const float* __restrict__ b2,
                                                  const float* __restrict__ w3,
                                                  const float* __restrict__ b3,
                                                  float* __restrict__ out, int G) {
  __shared__ float sG[64 * 64];
  __shared__ float sH1[64 * 32];
  __shared__ float sH2[64 * 16];
  int t = threadIdx.x;
  for (int i = t; i < G * 64; i += 256) sG[i] = g[i];
  __syncthreads();
  for (int o = t; o < G * 32; o += 256) {
    int gi = o >> 5, i = o & 31;
    float a = b1[i];
    for (int k = 0; k < 64; ++k) a += sG[gi * 64 + k] * w1[i * 64 + k];
    sH1[gi * 32 + i] = eluf_(a);
  }
  __syncthreads();
  for (int o = t; o < G * 16; o += 256) {
    int gi = o >> 4, i = o & 15;
    float a = b2[i];
    for (int k = 0; k < 32; ++k) a += sH1[gi * 32 + k] * w2[i * 32 + k];
    sH2[gi * 16 + i] = eluf_(a);
  }
  __syncthreads();
  for (int o = t; o < G; o += 256) {
    float a = b3[0];
    for (int k = 0; k < 16; ++k) a += sH2[o * 16 + k] * w3[k];
    out[o] = a;
  }
}

extern "C" void kernel_launch(void* const* d_in, const int* in_sizes, int n_in,
                              void* d_out, int out_size, void* d_ws, size_t ws_size,
                              hipStream_t stream) {
  const float* conv_w = (const float*)d_in[0];
  const float* w_ih = (const float*)d_in[1];
  const float* w_hh = (const float*)d_in[2];
  const float* b_ih = (const float*)d_in[3];
  const float* b_hh = (const float*)d_in[4];
  const float* fc1_w = (const float*)d_in[5];
  const float* fc1_b = (const float*)d_in[6];
  const float* fc2_w = (const float*)d_in[7];
  const float* fc2_b = (const float*)d_in[8];
  const float* fc3_w = (const float*)d_in[9];
  const float* fc3_b = (const float*)d_in[10];
  const int* ei = (const int*)d_in[11];
  const int* batch = (const int*)d_in[12];
  const int N = in_sizes[12];
  const int E = in_sizes[11] / 2;
  const int G = out_size;
  const int* src = ei;
  const int* dst = ei + E;
  const int nbk = (N + 1023) >> CBITS;
  const int tiles = (N + 63) / 64;
  const int Npad = tiles * 64;

  char* ws = (char*)d_ws;
  size_t off = 0;
  auto alloc = [&](size_t bytes) -> void* {
    void* p = ws + off;
    off += (bytes + 255) & ~(size_t)255;
    return p;
  };
  _Float16* xh = (_Float16*)alloc((size_t)Npad * 64 * 2);
  _Float16* aggh = (_Float16*)alloc((size_t)Npad * 64 * 2);
  _Float16* wcS = (_Float16*)alloc((size_t)5 * MATSZ * 2);
  _Float16* whhS = (_Float16*)alloc((size_t)5 * MATSZ * 2);
  float* h1 = (float*)alloc(64 * 4);
  float* gbuf = (float*)alloc((size_t)G * 64 * 4);
  int* offs = (int*)alloc((size_t)(N + 1) * 4);
  int* srcs = (int*)alloc((size_t)(E + 64) * 4);
  unsigned* pairs = (unsigned*)alloc((size_t)E * 4);
  int* bh = (int*)alloc(128 * 16 * 4);
  int* boffs = (int*)alloc(129 * 4);

  // --- CSR build ---
  hipMemsetAsync(bh, 0, 128 * 16 * 4, stream);
  bucket_hist_kernel<<<256, 256, 0, stream>>>(dst, bh, E);
  bucket_scan_kernel<<<1, 128, 0, stream>>>(bh, nbk, boffs, E);
  bucket_fill_kernel<<<(E + FCHUNK - 1) / FCHUNK, 256, 0, stream>>>(src, dst, bh, pairs, E);
  csr_build_kernel<<<nbk, 256, 0, stream>>>(pairs, boffs, offs, srcs, N, E);

  // --- weight prep: padded f16 images ---
  fuse_w_kernel<<<20, 256, 0, stream>>>(conv_w, w_ih, wcS);
  whh_prep_kernel<<<60, 256, 0, stream>>>(w_hh, whhS);

  // --- layer 0 (closed form) + layer-1 aggregate (deg * h1), merged ---
  h1_kernel<<<1, 64, 0, stream>>>(b_ih, b_hh, h1);
  bcast_kernel<<<(Npad * 32 + 255) / 256, 256, 0, stream>>>(offs, h1, xh, aggh, N, Npad * 32);

  gru_kernel<<<768, 256, 0, stream>>>(aggh, xh, wcS + MATSZ, whhS + MATSZ,
                                      b_ih + 192, b_hh + 192, N, tiles);
  for (int l = 2; l < 5; ++l) {
    agg_kernel<<<(N + 3) / 4, 256, 0, stream>>>(xh, offs, srcs, aggh, N);
    gru_kernel<<<768, 256, 0, stream>>>(aggh, xh, wcS + (size_t)l * MATSZ,
                                        whhS + (size_t)l * MATSZ, b_ih + (size_t)l * 192,
                                        b_hh + (size_t)l * 192, N, tiles);
  }

  hipMemsetAsync(gbuf, 0, (size_t)G * 64 * 4, stream);
  pool_kernel<<<(N + 63) / 64, 256, 0, stream>>>(xh, batch, gbuf, N);
  mlp_kernel<<<1, 256, 0, stream>>>(gbuf, fc1_w, fc1_b, fc2_w, fc2_b, fc3_w, fc3_b,
                                    (float*)d_out, G);
}

// Round 10
// 423.419 us; speedup vs baseline: 1.8101x; 1.0581x over previous
//
#include <hip/hip_runtime.h>
#include <math.h>

typedef _Float16 f16x2 __attribute__((ext_vector_type(2)));
typedef _Float16 f16x4 __attribute__((ext_vector_type(4)));
typedef _Float16 f16x8 __attribute__((ext_vector_type(8)));
typedef float f32x4 __attribute__((ext_vector_type(4)));

#define CBITS 10      // 1024 nodes per coarse bucket
#define FCHUNK 4096   // edges per fill block (32KB LDS staging)
// padded weight image: addr(row,col) = 64*row + 8*(row>>1) + col  (f16 units)
// size per 192x64 matrix: 192*64 + 96*8 = 13056 f16 = 26112 B
#define MATSZ 13056
__device__ __forceinline__ int woff(int row) { return 64 * row + 8 * (row >> 1); }

__device__ __forceinline__ float sigmoidf_(float v) {
  return 1.0f / (1.0f + __expf(-v));
}
__device__ __forceinline__ float tanhf_(float v) {
  v = fminf(fmaxf(v, -15.f), 15.f);
  float e = __expf(2.f * v);
  return (e - 1.f) / (e + 1.f);
}
__device__ __forceinline__ float eluf_(float v) { return v > 0.f ? v : (__expf(v) - 1.f); }

// ---------------- fuse conv into GRU input weights, output padded f16 image ----------------
// Wc[j][c] = sum_k conv_w[c][k] * w_ih[j][k]
__global__ __launch_bounds__(256) void fuse_w_kernel(const float* __restrict__ conv_w,
                                                     const float* __restrict__ w_ih,
                                                     _Float16* __restrict__ wcS) {
  const int l = blockIdx.x >> 2;
  const int j0 = (blockIdx.x & 3) * 48;
  const float* W = conv_w + (size_t)l * 4096;   // [c][k]
  const float* wi = w_ih + (size_t)l * 12288;   // [j][k]
  _Float16* out = wcS + (size_t)l * MATSZ;
  __shared__ float sWt[64 * 68];
  __shared__ float sI[48 * 64];
  const int t = threadIdx.x;
  for (int i = t; i < 4096; i += 256) sWt[(i & 63) * 68 + (i >> 6)] = W[i];
  for (int i = t; i < 3072; i += 256) sI[i] = wi[j0 * 64 + i];
  __syncthreads();
#pragma unroll
  for (int r = 0; r < 3; ++r) {
    int u = t + 256 * r;
    int j = u >> 4, cg = (u & 15) * 4;
    float4 a = {0.f, 0.f, 0.f, 0.f};
    for (int k = 0; k < 64; ++k) {
      float4 w = *(const float4*)(sWt + k * 68 + cg);
      float s = sI[j * 64 + k];
      a.x += w.x * s; a.y += w.y * s; a.z += w.z * s; a.w += w.w * s;
    }
    int row = j0 + j;
    f16x4 hv;
    hv[0] = (_Float16)a.x; hv[1] = (_Float16)a.y;
    hv[2] = (_Float16)a.z; hv[3] = (_Float16)a.w;
    *(f16x4*)(out + woff(row) + cg) = hv;
  }
}

// convert whh (f32) to padded f16 image
__global__ __launch_bounds__(256) void whh_prep_kernel(const float* __restrict__ whh,
                                                       _Float16* __restrict__ whhS) {
  int idx = blockIdx.x * 256 + threadIdx.x;  // 5 layers * 192 rows * 16 c4 = 15360
  if (idx >= 15360) return;
  int l = idx / 3072, rem = idx % 3072;
  int r = rem >> 4, c4 = (rem & 15) * 4;
  float4 v = *(const float4*)(whh + (size_t)l * 12288 + r * 64 + c4);
  f16x4 hv;
  hv[0] = (_Float16)v.x; hv[1] = (_Float16)v.y;
  hv[2] = (_Float16)v.z; hv[3] = (_Float16)v.w;
  *(f16x4*)(whhS + (size_t)l * MATSZ + woff(r) + c4) = hv;
}

// ---------------- CSR build: coarse-bucket counting sort ----------------
__global__ __launch_bounds__(256) void bucket_hist_kernel(const int* __restrict__ dst,
                                                          int* __restrict__ bh, int E) {
  __shared__ int h[128];
  const int t = threadIdx.x;
  if (t < 128) h[t] = 0;
  __syncthreads();
  for (int e = blockIdx.x * 256 + t; e < E; e += gridDim.x * 256)
    atomicAdd(&h[dst[e] >> CBITS], 1);
  __syncthreads();
  if (t < 128 && h[t]) atomicAdd(&bh[t * 16], h[t]);  // padded counters: 1 line each
}

__global__ __launch_bounds__(128) void bucket_scan_kernel(int* __restrict__ bh, int nbk,
                                                          int* __restrict__ boffs, int E) {
  __shared__ int s[128];
  const int t = threadIdx.x;
  int v = (t < nbk) ? bh[t * 16] : 0;
  s[t] = v;
  __syncthreads();
  for (int o = 1; o < 128; o <<= 1) {
    int a = (t >= o) ? s[t - o] : 0;
    __syncthreads();
    s[t] += a;
    __syncthreads();
  }
  if (t < nbk) {
    int ex = s[t] - v;
    boffs[t] = ex;
    bh[t * 16] = ex;  // becomes the reservation cursor
  }
  if (t == 0) boffs[nbk] = E;
}

__global__ __launch_bounds__(256) void bucket_fill_kernel(const int* __restrict__ src,
                                                          const int* __restrict__ dst,
                                                          int* __restrict__ bcur,
                                                          unsigned* __restrict__ pairs, int E) {
  __shared__ uint2 staged[FCHUNK];
  __shared__ int h[128], lbase[128], gbase[128], lcur[128];
  const int t = threadIdx.x;
  const int e0 = blockIdx.x * FCHUNK;
  int cnt = E - e0;
  if (cnt > FCHUNK) cnt = FCHUNK;
  if (t < 128) h[t] = 0;
  __syncthreads();
  for (int i = t; i < cnt; i += 256) atomicAdd(&h[dst[e0 + i] >> CBITS], 1);
  __syncthreads();
  if (t < 128) lcur[t] = h[t];
  __syncthreads();
  for (int o = 1; o < 128; o <<= 1) {
    int a = 0;
    if (t < 128 && t >= o) a = lcur[t - o];
    __syncthreads();
    if (t < 128) lcur[t] += a;
    __syncthreads();
  }
  if (t < 128) {
    int ex = lcur[t] - h[t];
    lbase[t] = ex;
    if (h[t]) gbase[t] = atomicAdd(&bcur[t * 16], h[t]);
    lcur[t] = ex;
  }
  __syncthreads();
  for (int i = t; i < cnt; i += 256) {
    int d = dst[e0 + i];
    int b = d >> CBITS;
    int p = atomicAdd(&lcur[b], 1);
    staged[p] = make_uint2((unsigned)src[e0 + i], (unsigned)d);
  }
  __syncthreads();
  // flush: consecutive staged positions within a bucket -> consecutive global positions
  for (int i = t; i < cnt; i += 256) {
    uint2 pr = staged[i];
    int b = (int)(pr.y >> CBITS);
    pairs[gbase[b] + (i - lbase[b])] = (pr.x << CBITS) | (pr.y & ((1u << CBITS) - 1));
  }
}

__global__ __launch_bounds__(256) void csr_build_kernel(const unsigned* __restrict__ pairs,
                                                        const int* __restrict__ boffs,
                                                        int* __restrict__ offs,
                                                        int* __restrict__ srcs, int N, int E) {
  const int b = blockIdx.x, t = threadIdx.x;
  const int nbase = b << CBITS;
  __shared__ int deg[1024];
  __shared__ int ssc[256];
  for (int i = t; i < 1024; i += 256) deg[i] = 0;
  __syncthreads();
  const int beg = boffs[b], end = boffs[b + 1];
  for (int e = beg + t; e < end; e += 256) atomicAdd(&deg[pairs[e] & 1023], 1);
  __syncthreads();
  int d0 = deg[4 * t], d1 = deg[4 * t + 1], d2 = deg[4 * t + 2], d3 = deg[4 * t + 3];
  int s = d0 + d1 + d2 + d3;
  ssc[t] = s;
  __syncthreads();
  for (int o = 1; o < 256; o <<= 1) {
    int a = (t >= o) ? ssc[t - o] : 0;
    __syncthreads();
    ssc[t] += a;
    __syncthreads();
  }
  int base = beg + ssc[t] - s;
  int c0 = base, c1 = c0 + d0, c2 = c1 + d1, c3 = c2 + d2;
  if (nbase + 4 * t + 0 < N) offs[nbase + 4 * t + 0] = c0;
  if (nbase + 4 * t + 1 < N) offs[nbase + 4 * t + 1] = c1;
  if (nbase + 4 * t + 2 < N) offs[nbase + 4 * t + 2] = c2;
  if (nbase + 4 * t + 3 < N) offs[nbase + 4 * t + 3] = c3;
  deg[4 * t] = c0; deg[4 * t + 1] = c1; deg[4 * t + 2] = c2; deg[4 * t + 3] = c3;
  if (b == 0 && t == 0) offs[N] = E;
  // zero-pad srcs tail: agg reads srcs[beg..beg+deg+63] — pad must be valid node ids
  if (b == 0 && t < 64) srcs[E + t] = 0;
  __syncthreads();
  for (int e = beg + t; e < end; e += 256) {
    unsigned p = pairs[e];
    int pos = atomicAdd(&deg[p & 1023], 1);
    srcs[pos] = (int)(p >> CBITS);
  }
}

// ---------------- layer-0 algebra: h1 = GRU(0, 0) is one 64-vector ----------------
__global__ __launch_bounds__(64) void h1_kernel(const float* __restrict__ b_ih,
                                                const float* __restrict__ b_hh,
                                                float* __restrict__ h1) {
  int d = threadIdx.x;
  float r = sigmoidf_(b_ih[d] + b_hh[d]);
  float z = sigmoidf_(b_ih[64 + d] + b_hh[64 + d]);
  float n = tanhf_(b_ih[128 + d] + r * b_hh[128 + d]);
  h1[d] = (1.f - z) * n;
}

// broadcast h1 into xh AND write layer-1 aggregate aggh = deg * h1 (merged kernel)
__global__ __launch_bounds__(256) void bcast_kernel(const int* __restrict__ offs,
                                                    const float* __restrict__ h1,
                                                    _Float16* __restrict__ xh,
                                                    _Float16* __restrict__ aggh,
                                                    int N, int units) {
  int idx = blockIdx.x * 256 + threadIdx.x;  // one f16x2 (2 dims) per thread
  if (idx >= units) return;
  int v = idx >> 5, lp = idx & 31;
  float2 hh = *(const float2*)(h1 + lp * 2);
  f16x2 hv;
  hv[0] = (_Float16)hh.x; hv[1] = (_Float16)hh.y;
  *(f16x2*)(xh + (size_t)idx * 2) = hv;
  float dg = (v < N) ? (float)(offs[v + 1] - offs[v]) : 0.f;
  f16x2 av;
  av[0] = (_Float16)(dg * hh.x); av[1] = (_Float16)(dg * hh.y);
  *(f16x2*)(aggh + (size_t)idx * 2) = av;
}

// ---------------- aggregate v3: 8 edges per load (f16x8/lane), packed-f16 accumulate ----------------
__global__ __launch_bounds__(256) void agg_kernel(const _Float16* __restrict__ xh,
                                                  const int* __restrict__ offs,
                                                  const int* __restrict__ srcs,
                                                  _Float16* __restrict__ aggh, int N) {
  int wave = threadIdx.x >> 6, lane = threadIdx.x & 63;
  int v = blockIdx.x * 4 + wave;
  if (v >= N) return;
  const int beg = offs[v], end = offs[v + 1];
  const int deg = end - beg;
  const int og = lane >> 3;   // edge slot (0..7) this lane serves
  const int lp = lane & 7;    // f16x8 chunk within the 128B row
  f16x8 acc = {};
  for (int base = 0; base < deg; base += 64) {
    const int cnt = min(64, deg - base);
    int sidx = srcs[beg + base + lane];  // one vector load: 64 indices (srcs zero-padded +64)
    for (int e = 0; e < cnt; e += 8) {
      int me = e + og;
      int s = __shfl(sidx, me);          // pad lanes give s=0: valid row, masked below
      f16x8 vv = *(const f16x8*)(xh + (size_t)s * 64 + lp * 8);
      if (me < cnt) acc += vv;           // 4x v_pk_add_f16
    }
  }
  // reduce across the 8 edge slots (lanes lp, lp+8, ..., lp+56)
#pragma unroll
  for (int off = 8; off < 64; off <<= 1) {
    union { f16x8 h; int i[4]; } a, b;
    a.h = acc;
#pragma unroll
    for (int w = 0; w < 4; ++w) b.i[w] = __shfl_xor(a.i[w], off);
    acc += b.h;
  }
  if (og == 0) *(f16x8*)(aggh + (size_t)v * 64 + lp * 8) = acc;  // 8 lanes x 16B contiguous
}

// ---------------- MFMA GRU: xh_out = GRUCell(aggh @ Wc^T, xh_in) ----------------
// PING-PONG state: reads xh_in, writes xh_out (round 9's in-place half-split raced:
// block (tile,0) wrote dims 0-31 while block (tile,1) was reading the full old row).
// (tile, half) iteration halves live accumulators (10 f32x4) for VGPR relief.
// No min-occupancy forcing (round 6: forcing -> 300MB/dispatch scratch spill).
__global__ __launch_bounds__(256) void gru_kernel(const _Float16* __restrict__ aggh,
                                                  const _Float16* __restrict__ xh_in,
                                                  _Float16* __restrict__ xh_out,
                                                  const _Float16* __restrict__ wcS,
                                                  const _Float16* __restrict__ whhS,
                                                  const float* __restrict__ b_ih,
                                                  const float* __restrict__ b_hh,
                                                  int N, int numIter) {
  __shared__ _Float16 sW[2 * MATSZ];  // 51 KB
  const int t = threadIdx.x;
  for (int i = t; i < 2 * (MATSZ / 8); i += 256) {  // straight b128 copy
    int mat = (i >= MATSZ / 8);
    int idx = i - mat * (MATSZ / 8);
    *(f16x8*)(sW + mat * MATSZ + idx * 8) =
        *(const f16x8*)((mat ? whhS : wcS) + idx * 8);
  }
  __syncthreads();
  const int wave = t >> 6, lane = t & 63;
  const int q = lane >> 4, c = lane & 15;
  // biases (all 16; per-iteration 2-way select on `half`)
  float bRZ[4], bZZ[4], bIN[4], bHN[4];
#pragma unroll
  for (int dt = 0; dt < 4; ++dt) {
    int d = dt * 16 + c;
    bRZ[dt] = b_ih[d] + b_hh[d];
    bZZ[dt] = b_ih[64 + d] + b_hh[64 + d];
    bIN[dt] = b_ih[128 + d];
    bHN[dt] = b_hh[128 + d];
  }
  // identity B-frags: tgt depends only on p = dt&1
  f16x8 idf[2];
#pragma unroll
  for (int p = 0; p < 2; ++p) {
    int tgt = p * 16 + c - q * 8;
#pragma unroll
    for (int j = 0; j < 8; ++j) idf[p][j] = (j == tgt) ? (_Float16)1.0f : (_Float16)0.0f;
  }
#pragma unroll 1
  for (int it = blockIdx.x; it < numIter; it += gridDim.x) {
    const int tile = it >> 1, half = it & 1;
    const int nb0 = tile * 64 + wave * 16;
    const size_t rowbase = (size_t)(nb0 + c) * 64;
    f16x8 aA[2], aH[2];
#pragma unroll
    for (int ks = 0; ks < 2; ++ks) {
      aA[ks] = *(const f16x8*)(aggh + rowbase + ks * 32 + q * 8);
      aH[ks] = *(const f16x8*)(xh_in + rowbase + ks * 32 + q * 8);
    }
    f32x4 aR[2], aZ[2], aN[2], aHNa[2], aHO[2];
#pragma unroll
    for (int p = 0; p < 2; ++p) {
      float brz = half ? bRZ[2 + p] : bRZ[p];
      float bzz = half ? bZZ[2 + p] : bZZ[p];
      float bin = half ? bIN[2 + p] : bIN[p];
      float bhn = half ? bHN[2 + p] : bHN[p];
      aR[p] = (f32x4){brz, brz, brz, brz};
      aZ[p] = (f32x4){bzz, bzz, bzz, bzz};
      aN[p] = (f32x4){bin, bin, bin, bin};
      aHNa[p] = (f32x4){bhn, bhn, bhn, bhn};
      aHO[p] = (f32x4){0.f, 0.f, 0.f, 0.f};
    }
#pragma unroll
    for (int ks = 0; ks < 2; ++ks) {
      const int colo = ks * 32 + q * 8;
#pragma unroll
      for (int p = 0; p < 2; ++p) {
        const int r0 = (half * 2 + p) * 16 + c;
        f16x8 bWr = *(const f16x8*)(sW + woff(r0) + colo);
        f16x8 bHr = *(const f16x8*)(sW + MATSZ + woff(r0) + colo);
        f16x8 bWz = *(const f16x8*)(sW + woff(64 + r0) + colo);
        f16x8 bHz = *(const f16x8*)(sW + MATSZ + woff(64 + r0) + colo);
        f16x8 bWn = *(const f16x8*)(sW + woff(128 + r0) + colo);
        f16x8 bHn = *(const f16x8*)(sW + MATSZ + woff(128 + r0) + colo);
        aR[p] = __builtin_amdgcn_mfma_f32_16x16x32_f16(aA[ks], bWr, aR[p], 0, 0, 0);
        aR[p] = __builtin_amdgcn_mfma_f32_16x16x32_f16(aH[ks], bHr, aR[p], 0, 0, 0);
        aZ[p] = __builtin_amdgcn_mfma_f32_16x16x32_f16(aA[ks], bWz, aZ[p], 0, 0, 0);
        aZ[p] = __builtin_amdgcn_mfma_f32_16x16x32_f16(aH[ks], bHz, aZ[p], 0, 0, 0);
        aN[p] = __builtin_amdgcn_mfma_f32_16x16x32_f16(aA[ks], bWn, aN[p], 0, 0, 0);
        aHNa[p] = __builtin_amdgcn_mfma_f32_16x16x32_f16(aH[ks], bHn, aHNa[p], 0, 0, 0);
      }
    }
#pragma unroll
    for (int p = 0; p < 2; ++p)
      aHO[p] = __builtin_amdgcn_mfma_f32_16x16x32_f16(aH[half], idf[p], aHO[p], 0, 0, 0);
    // epilogue: lane (q,c) holds D[node = nb0 + q*4+r][dim = (half*2+p)*16+c]
#pragma unroll
    for (int p = 0; p < 2; ++p) {
      int d = (half * 2 + p) * 16 + c;
#pragma unroll
      for (int r = 0; r < 4; ++r) {
        int node = nb0 + q * 4 + r;
        if (node < N) {
          float rr = sigmoidf_(aR[p][r]);
          float zz = sigmoidf_(aZ[p][r]);
          float nn = tanhf_(aN[p][r] + rr * aHNa[p][r]);
          float out = nn + zz * (aHO[p][r] - nn);
          xh_out[(size_t)node * 64 + d] = (_Float16)out;
        }
      }
    }
  }
}

// ---------------- pooling (f16 input) ----------------
__global__ __launch_bounds__(256) void pool_kernel(const _Float16* __restrict__ xh,
                                                   const int* __restrict__ batch,
                                                   float* __restrict__ g, int N) {
  int wave = threadIdx.x >> 6, lane = threadIdx.x & 63;
  int n0 = blockIdx.x * 64 + wave * 16;
  if (n0 >= N) return;
  int end = n0 + 16;
  if (end > N) end = N;
  int cur = batch[n0];
  float acc = 0.f;
  for (int n = n0; n < end; ++n) {
    int b = batch[n];
    if (b != cur) {
      atomicAdd(&g[(size_t)cur * 64 + lane], acc);
      acc = 0.f;
      cur = b;
    }
    acc += (float)xh[(size_t)n * 64 + lane];
  }
  atomicAdd(&g[(size_t)cur * 64 + lane], acc);
}

// ---------------- final MLP ----------------
__global__ __launch_bounds__(256) void mlp_kernel(const float* __restrict__ g,
                                                  const float* __restrict__ w1,
                                                  const float* __restrict__ b1,
                                                  const float* __restrict__ w2,
                                                  const float* __restrict__ b2,
                                                  const float* __restrict__ w3,
                                                  const float* __restrict__ b3,
                                                  float* __restrict__ out, int G) {
  __shared__ float sG[64 * 64];
  __shared__ float sH1[64 * 32];
  __shared__ float sH2[64 * 16];
  int t = threadIdx.x;
  for (int i = t; i < G * 64; i += 256) sG[i] = g[i];
  __syncthreads();
  for (int o = t; o < G * 32; o += 256) {
    int gi = o >> 5, i = o & 31;
    float a = b1[i];
    for (int k = 0; k < 64; ++k) a += sG[gi * 64 + k] * w1[i * 64 + k];
    sH1[gi * 32 + i] = eluf_(a);
  }
  __syncthreads();
  for (int o = t; o < G * 16; o += 256) {
    int gi = o >> 4, i = o & 15;
    float a = b2[i];
    for (int k = 0; k < 32; ++k) a += sH1[gi * 32 + k] * w2[i * 32 + k];
    sH2[gi * 16 + i] = eluf_(a);
  }
  __syncthreads();
  for (int o = t; o < G; o += 256) {
    float a = b3[0];
    for (int k = 0; k < 16; ++k) a += sH2[o * 16 + k] * w3[k];
    out[o] = a;
  }
}

extern "C" void kernel_launch(void* const* d_in, const int* in_sizes, int n_in,
                              void* d_out, int out_size, void* d_ws, size_t ws_size,
                              hipStream_t stream) {
  const float* conv_w = (const float*)d_in[0];
  const float* w_ih = (const float*)d_in[1];
  const float* w_hh = (const float*)d_in[2];
  const float* b_ih = (const float*)d_in[3];
  const float* b_hh = (const float*)d_in[4];
  const float* fc1_w = (const float*)d_in[5];
  const float* fc1_b = (const float*)d_in[6];
  const float* fc2_w = (const float*)d_in[7];
  const float* fc2_b = (const float*)d_in[8];
  const float* fc3_w = (const float*)d_in[9];
  const float* fc3_b = (const float*)d_in[10];
  const int* ei = (const int*)d_in[11];
  const int* batch = (const int*)d_in[12];
  const int N = in_sizes[12];
  const int E = in_sizes[11] / 2;
  const int G = out_size;
  const int* src = ei;
  const int* dst = ei + E;
  const int nbk = (N + 1023) >> CBITS;
  const int tiles = (N + 63) / 64;
  const int Npad = tiles * 64;
  const int gruIter = tiles * 2;

  char* ws = (char*)d_ws;
  size_t off = 0;
  auto alloc = [&](size_t bytes) -> void* {
    void* p = ws + off;
    off += (bytes + 255) & ~(size_t)255;
    return p;
  };
  _Float16* xhA = (_Float16*)alloc((size_t)Npad * 64 * 2);
  _Float16* xhB = (_Float16*)alloc((size_t)Npad * 64 * 2);
  _Float16* aggh = (_Float16*)alloc((size_t)Npad * 64 * 2);
  _Float16* wcS = (_Float16*)alloc((size_t)5 * MATSZ * 2);
  _Float16* whhS = (_Float16*)alloc((size_t)5 * MATSZ * 2);
  float* h1 = (float*)alloc(64 * 4);
  float* gbuf = (float*)alloc((size_t)G * 64 * 4);
  int* offs = (int*)alloc((size_t)(N + 1) * 4);
  int* srcs = (int*)alloc((size_t)(E + 64) * 4);
  unsigned* pairs = (unsigned*)alloc((size_t)E * 4);
  int* bh = (int*)alloc(128 * 16 * 4);
  int* boffs = (int*)alloc(129 * 4);

  // --- CSR build ---
  hipMemsetAsync(bh, 0, 128 * 16 * 4, stream);
  bucket_hist_kernel<<<256, 256, 0, stream>>>(dst, bh, E);
  bucket_scan_kernel<<<1, 128, 0, stream>>>(bh, nbk, boffs, E);
  bucket_fill_kernel<<<(E + FCHUNK - 1) / FCHUNK, 256, 0, stream>>>(src, dst, bh, pairs, E);
  csr_build_kernel<<<nbk, 256, 0, stream>>>(pairs, boffs, offs, srcs, N, E);

  // --- weight prep: padded f16 images ---
  fuse_w_kernel<<<20, 256, 0, stream>>>(conv_w, w_ih, wcS);
  whh_prep_kernel<<<60, 256, 0, stream>>>(w_hh, whhS);

  // --- layer 0 (closed form) + layer-1 aggregate (deg * h1), merged ---
  h1_kernel<<<1, 64, 0, stream>>>(b_ih, b_hh, h1);
  bcast_kernel<<<(Npad * 32 + 255) / 256, 256, 0, stream>>>(offs, h1, xhA, aggh, N, Npad * 32);

  // ping-pong: L1 A->B, L2 B->A, L3 A->B, L4 B->A; pool reads A
  _Float16* cur = xhA;
  _Float16* nxt = xhB;
  gru_kernel<<<768, 256, 0, stream>>>(aggh, cur, nxt, wcS + MATSZ, whhS + MATSZ,
                                      b_ih + 192, b_hh + 192, N, gruIter);
  { _Float16* tmp = cur; cur = nxt; nxt = tmp; }
  for (int l = 2; l < 5; ++l) {
    agg_kernel<<<(N + 3) / 4, 256, 0, stream>>>(cur, offs, srcs, aggh, N);
    gru_kernel<<<768, 256, 0, stream>>>(aggh, cur, nxt, wcS + (size_t)l * MATSZ,
                                        whhS + (size_t)l * MATSZ, b_ih + (size_t)l * 192,
                                        b_hh + (size_t)l * 192, N, gruIter);
    _Float16* tmp = cur; cur = nxt; nxt = tmp;
  }

  hipMemsetAsync(gbuf, 0, (size_t)G * 64 * 4, stream);
  pool_kernel<<<(N + 63) / 64, 256, 0, stream>>>(cur, batch, gbuf, N);
  mlp_kernel<<<1, 256, 0, stream>>>(gbuf, fc1_w, fc1_b, fc2_w, fc2_b, fc3_w, fc3_b,
                                    (float*)d_out, G);
}

// Round 11
// 409.499 us; speedup vs baseline: 1.8717x; 1.0340x over previous
//
#include <hip/hip_runtime.h>
#include <math.h>

typedef _Float16 f16x2 __attribute__((ext_vector_type(2)));
typedef _Float16 f16x4 __attribute__((ext_vector_type(4)));
typedef _Float16 f16x8 __attribute__((ext_vector_type(8)));
typedef float f32x4 __attribute__((ext_vector_type(4)));

#define CBITS 10      // 1024 nodes per coarse bucket
#define FCHUNK 4096   // edges per fill block (32KB LDS staging)
// padded weight image: addr(row,col) = 64*row + 8*(row>>1) + col  (f16 units)
// size per 192x64 matrix: 192*64 + 96*8 = 13056 f16 = 26112 B
#define MATSZ 13056
__device__ __forceinline__ int woff(int row) { return 64 * row + 8 * (row >> 1); }

__device__ __forceinline__ float sigmoidf_(float v) {
  return 1.0f / (1.0f + __expf(-v));
}
__device__ __forceinline__ float tanhf_(float v) {
  v = fminf(fmaxf(v, -15.f), 15.f);
  float e = __expf(2.f * v);
  return (e - 1.f) / (e + 1.f);
}
__device__ __forceinline__ float eluf_(float v) { return v > 0.f ? v : (__expf(v) - 1.f); }

// ---------------- fuse conv into GRU input weights, output padded f16 image ----------------
// Wc[j][c] = sum_k conv_w[c][k] * w_ih[j][k]
__global__ __launch_bounds__(256) void fuse_w_kernel(const float* __restrict__ conv_w,
                                                     const float* __restrict__ w_ih,
                                                     _Float16* __restrict__ wcS) {
  const int l = blockIdx.x >> 2;
  const int j0 = (blockIdx.x & 3) * 48;
  const float* W = conv_w + (size_t)l * 4096;   // [c][k]
  const float* wi = w_ih + (size_t)l * 12288;   // [j][k]
  _Float16* out = wcS + (size_t)l * MATSZ;
  __shared__ float sWt[64 * 68];
  __shared__ float sI[48 * 64];
  const int t = threadIdx.x;
  for (int i = t; i < 4096; i += 256) sWt[(i & 63) * 68 + (i >> 6)] = W[i];
  for (int i = t; i < 3072; i += 256) sI[i] = wi[j0 * 64 + i];
  __syncthreads();
#pragma unroll
  for (int r = 0; r < 3; ++r) {
    int u = t + 256 * r;
    int j = u >> 4, cg = (u & 15) * 4;
    float4 a = {0.f, 0.f, 0.f, 0.f};
    for (int k = 0; k < 64; ++k) {
      float4 w = *(const float4*)(sWt + k * 68 + cg);
      float s = sI[j * 64 + k];
      a.x += w.x * s; a.y += w.y * s; a.z += w.z * s; a.w += w.w * s;
    }
    int row = j0 + j;
    f16x4 hv;
    hv[0] = (_Float16)a.x; hv[1] = (_Float16)a.y;
    hv[2] = (_Float16)a.z; hv[3] = (_Float16)a.w;
    *(f16x4*)(out + woff(row) + cg) = hv;
  }
}

// convert whh (f32) to padded f16 image
__global__ __launch_bounds__(256) void whh_prep_kernel(const float* __restrict__ whh,
                                                       _Float16* __restrict__ whhS) {
  int idx = blockIdx.x * 256 + threadIdx.x;  // 5 layers * 192 rows * 16 c4 = 15360
  if (idx >= 15360) return;
  int l = idx / 3072, rem = idx % 3072;
  int r = rem >> 4, c4 = (rem & 15) * 4;
  float4 v = *(const float4*)(whh + (size_t)l * 12288 + r * 64 + c4);
  f16x4 hv;
  hv[0] = (_Float16)v.x; hv[1] = (_Float16)v.y;
  hv[2] = (_Float16)v.z; hv[3] = (_Float16)v.w;
  *(f16x4*)(whhS + (size_t)l * MATSZ + woff(r) + c4) = hv;
}

// ---------------- CSR build: coarse-bucket counting sort ----------------
__global__ __launch_bounds__(256) void bucket_hist_kernel(const int* __restrict__ dst,
                                                          int* __restrict__ bh, int E) {
  __shared__ int h[128];
  const int t = threadIdx.x;
  if (t < 128) h[t] = 0;
  __syncthreads();
  for (int e = blockIdx.x * 256 + t; e < E; e += gridDim.x * 256)
    atomicAdd(&h[dst[e] >> CBITS], 1);
  __syncthreads();
  if (t < 128 && h[t]) atomicAdd(&bh[t * 16], h[t]);  // padded counters: 1 line each
}

__global__ __launch_bounds__(128) void bucket_scan_kernel(int* __restrict__ bh, int nbk,
                                                          int* __restrict__ boffs, int E) {
  __shared__ int s[128];
  const int t = threadIdx.x;
  int v = (t < nbk) ? bh[t * 16] : 0;
  s[t] = v;
  __syncthreads();
  for (int o = 1; o < 128; o <<= 1) {
    int a = (t >= o) ? s[t - o] : 0;
    __syncthreads();
    s[t] += a;
    __syncthreads();
  }
  if (t < nbk) {
    int ex = s[t] - v;
    boffs[t] = ex;
    bh[t * 16] = ex;  // becomes the reservation cursor
  }
  if (t == 0) boffs[nbk] = E;
}

__global__ __launch_bounds__(256) void bucket_fill_kernel(const int* __restrict__ src,
                                                          const int* __restrict__ dst,
                                                          int* __restrict__ bcur,
                                                          unsigned* __restrict__ pairs, int E) {
  __shared__ uint2 staged[FCHUNK];
  __shared__ int h[128], lbase[128], gbase[128], lcur[128];
  const int t = threadIdx.x;
  const int e0 = blockIdx.x * FCHUNK;
  int cnt = E - e0;
  if (cnt > FCHUNK) cnt = FCHUNK;
  if (t < 128) h[t] = 0;
  __syncthreads();
  for (int i = t; i < cnt; i += 256) atomicAdd(&h[dst[e0 + i] >> CBITS], 1);
  __syncthreads();
  if (t < 128) lcur[t] = h[t];
  __syncthreads();
  for (int o = 1; o < 128; o <<= 1) {
    int a = 0;
    if (t < 128 && t >= o) a = lcur[t - o];
    __syncthreads();
    if (t < 128) lcur[t] += a;
    __syncthreads();
  }
  if (t < 128) {
    int ex = lcur[t] - h[t];
    lbase[t] = ex;
    if (h[t]) gbase[t] = atomicAdd(&bcur[t * 16], h[t]);
    lcur[t] = ex;
  }
  __syncthreads();
  for (int i = t; i < cnt; i += 256) {
    int d = dst[e0 + i];
    int b = d >> CBITS;
    int p = atomicAdd(&lcur[b], 1);
    staged[p] = make_uint2((unsigned)src[e0 + i], (unsigned)d);
  }
  __syncthreads();
  // flush: consecutive staged positions within a bucket -> consecutive global positions
  for (int i = t; i < cnt; i += 256) {
    uint2 pr = staged[i];
    int b = (int)(pr.y >> CBITS);
    pairs[gbase[b] + (i - lbase[b])] = (pr.x << CBITS) | (pr.y & ((1u << CBITS) - 1));
  }
}

__global__ __launch_bounds__(256) void csr_build_kernel(const unsigned* __restrict__ pairs,
                                                        const int* __restrict__ boffs,
                                                        int* __restrict__ offs,
                                                        int* __restrict__ srcs, int N, int E) {
  const int b = blockIdx.x, t = threadIdx.x;
  const int nbase = b << CBITS;
  __shared__ int deg[1024];
  __shared__ int ssc[256];
  for (int i = t; i < 1024; i += 256) deg[i] = 0;
  __syncthreads();
  const int beg = boffs[b], end = boffs[b + 1];
  for (int e = beg + t; e < end; e += 256) atomicAdd(&deg[pairs[e] & 1023], 1);
  __syncthreads();
  int d0 = deg[4 * t], d1 = deg[4 * t + 1], d2 = deg[4 * t + 2], d3 = deg[4 * t + 3];
  int s = d0 + d1 + d2 + d3;
  ssc[t] = s;
  __syncthreads();
  for (int o = 1; o < 256; o <<= 1) {
    int a = (t >= o) ? ssc[t - o] : 0;
    __syncthreads();
    ssc[t] += a;
    __syncthreads();
  }
  int base = beg + ssc[t] - s;
  int c0 = base, c1 = c0 + d0, c2 = c1 + d1, c3 = c2 + d2;
  if (nbase + 4 * t + 0 < N) offs[nbase + 4 * t + 0] = c0;
  if (nbase + 4 * t + 1 < N) offs[nbase + 4 * t + 1] = c1;
  if (nbase + 4 * t + 2 < N) offs[nbase + 4 * t + 2] = c2;
  if (nbase + 4 * t + 3 < N) offs[nbase + 4 * t + 3] = c3;
  deg[4 * t] = c0; deg[4 * t + 1] = c1; deg[4 * t + 2] = c2; deg[4 * t + 3] = c3;
  if (b == 0 && t == 0) offs[N] = E;
  // zero-pad srcs tail: agg reads srcs[beg..beg+deg+63] — pad must be valid node ids
  if (b == 0 && t < 64) srcs[E + t] = 0;
  __syncthreads();
  for (int e = beg + t; e < end; e += 256) {
    unsigned p = pairs[e];
    int pos = atomicAdd(&deg[p & 1023], 1);
    srcs[pos] = (int)(p >> CBITS);
  }
}

// ---------------- layer-0 algebra: h1 = GRU(0, 0) is one 64-vector ----------------
__global__ __launch_bounds__(64) void h1_kernel(const float* __restrict__ b_ih,
                                                const float* __restrict__ b_hh,
                                                float* __restrict__ h1) {
  int d = threadIdx.x;
  float r = sigmoidf_(b_ih[d] + b_hh[d]);
  float z = sigmoidf_(b_ih[64 + d] + b_hh[64 + d]);
  float n = tanhf_(b_ih[128 + d] + r * b_hh[128 + d]);
  h1[d] = (1.f - z) * n;
}

// ---------------- layer-1 algebra: h2[v] is a pure function of deg[v] ----------------
// gi = (deg*h1)@Wc^T = deg*u with u = h1@Wc^T; gh = h1@Whh^T = gh1 (const); hold = h1.
// Precompute u[192] and folded constants cons[256] = [cr|cz|cin|chn].
__global__ __launch_bounds__(256) void l1u_kernel(const _Float16* __restrict__ wcS1,
                                                  const _Float16* __restrict__ whhS1,
                                                  const float* __restrict__ h1,
                                                  const float* __restrict__ b_ih1,
                                                  const float* __restrict__ b_hh1,
                                                  float* __restrict__ u,
                                                  float* __restrict__ cons) {
  int j = threadIdx.x;
  if (j >= 192) return;
  float su = 0.f, sg = 0.f;
  const int base = woff(j);
  for (int c = 0; c < 64; ++c) {
    float hc = h1[c];
    su += hc * (float)wcS1[base + c];
    sg += hc * (float)whhS1[base + c];
  }
  u[j] = su;
  if (j < 128) {
    cons[j] = sg + b_ih1[j] + b_hh1[j];          // cr (j<64), cz (64..127)
  } else {
    cons[j] = b_ih1[j];                          // cin at 128..191
    cons[j + 64] = sg + b_hh1[j];                // chn at 192..255
  }
}

// h2[v][d] = n + z*(h1[d]-n);  r=sig(deg*u[d]+cr), z=sig(deg*u[64+d]+cz),
// n=tanh(deg*u[128+d]+cin + r*chn). Writes post-L1 state directly into xh.
__global__ __launch_bounds__(256) void l1_elem_kernel(const int* __restrict__ offs,
                                                      const float* __restrict__ h1,
                                                      const float* __restrict__ u,
                                                      const float* __restrict__ cons,
                                                      _Float16* __restrict__ xh,
                                                      int N, int units) {
  int idx = blockIdx.x * 256 + threadIdx.x;  // one f16x2 (2 dims) per thread
  if (idx >= units) return;
  int v = idx >> 5, lp = idx & 31;
  float dg = (v < N) ? (float)(offs[v + 1] - offs[v]) : 0.f;
  f16x2 o;
#pragma unroll
  for (int k = 0; k < 2; ++k) {
    int d = 2 * lp + k;
    float r = sigmoidf_(dg * u[d] + cons[d]);
    float z = sigmoidf_(dg * u[64 + d] + cons[64 + d]);
    float n = tanhf_(dg * u[128 + d] + cons[128 + d] + r * cons[192 + d]);
    o[k] = (_Float16)(n + z * (h1[d] - n));
  }
  *(f16x2*)(xh + (size_t)idx * 2) = o;
}

// ---------------- aggregate v3: 8 edges per load (f16x8/lane), packed-f16 accumulate ----------------
__global__ __launch_bounds__(256) void agg_kernel(const _Float16* __restrict__ xh,
                                                  const int* __restrict__ offs,
                                                  const int* __restrict__ srcs,
                                                  _Float16* __restrict__ aggh, int N) {
  int wave = threadIdx.x >> 6, lane = threadIdx.x & 63;
  int v = blockIdx.x * 4 + wave;
  if (v >= N) return;
  const int beg = offs[v], end = offs[v + 1];
  const int deg = end - beg;
  const int og = lane >> 3;   // edge slot (0..7) this lane serves
  const int lp = lane & 7;    // f16x8 chunk within the 128B row
  f16x8 acc = {};
  for (int base = 0; base < deg; base += 64) {
    const int cnt = min(64, deg - base);
    int sidx = srcs[beg + base + lane];  // one vector load: 64 indices (srcs zero-padded +64)
    for (int e = 0; e < cnt; e += 8) {
      int me = e + og;
      int s = __shfl(sidx, me);          // pad lanes give s=0: valid row, masked below
      f16x8 vv = *(const f16x8*)(xh + (size_t)s * 64 + lp * 8);
      if (me < cnt) acc += vv;           // 4x v_pk_add_f16
    }
  }
  // reduce across the 8 edge slots (lanes lp, lp+8, ..., lp+56)
#pragma unroll
  for (int off = 8; off < 64; off <<= 1) {
    union { f16x8 h; int i[4]; } a, b;
    a.h = acc;
#pragma unroll
    for (int w = 0; w < 4; ++w) b.i[w] = __shfl_xor(a.i[w], off);
    acc += b.h;
  }
  if (og == 0) *(f16x8*)(aggh + (size_t)v * 64 + lp * 8) = acc;  // 8 lanes x 16B contiguous
}

// ---------------- MFMA GRU: xh_out = GRUCell(aggh @ Wc^T, xh_in) ----------------
// PING-PONG state (in-place half-split raced in round 9).
// (tile, half) iteration halves live accumulators (10 f32x4) for VGPR relief.
// No min-occupancy forcing (round 6: forcing -> 300MB/dispatch scratch spill).
__global__ __launch_bounds__(256) void gru_kernel(const _Float16* __restrict__ aggh,
                                                  const _Float16* __restrict__ xh_in,
                                                  _Float16* __restrict__ xh_out,
                                                  const _Float16* __restrict__ wcS,
                                                  const _Float16* __restrict__ whhS,
                                                  const float* __restrict__ b_ih,
                                                  const float* __restrict__ b_hh,
                                                  int N, int numIter) {
  __shared__ _Float16 sW[2 * MATSZ];  // 51 KB
  const int t = threadIdx.x;
  for (int i = t; i < 2 * (MATSZ / 8); i += 256) {  // straight b128 copy
    int mat = (i >= MATSZ / 8);
    int idx = i - mat * (MATSZ / 8);
    *(f16x8*)(sW + mat * MATSZ + idx * 8) =
        *(const f16x8*)((mat ? whhS : wcS) + idx * 8);
  }
  __syncthreads();
  const int wave = t >> 6, lane = t & 63;
  const int q = lane >> 4, c = lane & 15;
  // biases (all 16; per-iteration 2-way select on `half`)
  float bRZ[4], bZZ[4], bIN[4], bHN[4];
#pragma unroll
  for (int dt = 0; dt < 4; ++dt) {
    int d = dt * 16 + c;
    bRZ[dt] = b_ih[d] + b_hh[d];
    bZZ[dt] = b_ih[64 + d] + b_hh[64 + d];
    bIN[dt] = b_ih[128 + d];
    bHN[dt] = b_hh[128 + d];
  }
  // identity B-frags: tgt depends only on p = dt&1
  f16x8 idf[2];
#pragma unroll
  for (int p = 0; p < 2; ++p) {
    int tgt = p * 16 + c - q * 8;
#pragma unroll
    for (int j = 0; j < 8; ++j) idf[p][j] = (j == tgt) ? (_Float16)1.0f : (_Float16)0.0f;
  }
#pragma unroll 1
  for (int it = blockIdx.x; it < numIter; it += gridDim.x) {
    const int tile = it >> 1, half = it & 1;
    const int nb0 = tile * 64 + wave * 16;
    const size_t rowbase = (size_t)(nb0 + c) * 64;
    f16x8 aA[2], aH[2];
#pragma unroll
    for (int ks = 0; ks < 2; ++ks) {
      aA[ks] = *(const f16x8*)(aggh + rowbase + ks * 32 + q * 8);
      aH[ks] = *(const f16x8*)(xh_in + rowbase + ks * 32 + q * 8);
    }
    f32x4 aR[2], aZ[2], aN[2], aHNa[2], aHO[2];
#pragma unroll
    for (int p = 0; p < 2; ++p) {
      float brz = half ? bRZ[2 + p] : bRZ[p];
      float bzz = half ? bZZ[2 + p] : bZZ[p];
      float bin = half ? bIN[2 + p] : bIN[p];
      float bhn = half ? bHN[2 + p] : bHN[p];
      aR[p] = (f32x4){brz, brz, brz, brz};
      aZ[p] = (f32x4){bzz, bzz, bzz, bzz};
      aN[p] = (f32x4){bin, bin, bin, bin};
      aHNa[p] = (f32x4){bhn, bhn, bhn, bhn};
      aHO[p] = (f32x4){0.f, 0.f, 0.f, 0.f};
    }
#pragma unroll
    for (int ks = 0; ks < 2; ++ks) {
      const int colo = ks * 32 + q * 8;
#pragma unroll
      for (int p = 0; p < 2; ++p) {
        const int r0 = (half * 2 + p) * 16 + c;
        f16x8 bWr = *(const f16x8*)(sW + woff(r0) + colo);
        f16x8 bHr = *(const f16x8*)(sW + MATSZ + woff(r0) + colo);
        f16x8 bWz = *(const f16x8*)(sW + woff(64 + r0) + colo);
        f16x8 bHz = *(const f16x8*)(sW + MATSZ + woff(64 + r0) + colo);
        f16x8 bWn = *(const f16x8*)(sW + woff(128 + r0) + colo);
        f16x8 bHn = *(const f16x8*)(sW + MATSZ + woff(128 + r0) + colo);
        aR[p] = __builtin_amdgcn_mfma_f32_16x16x32_f16(aA[ks], bWr, aR[p], 0, 0, 0);
        aR[p] = __builtin_amdgcn_mfma_f32_16x16x32_f16(aH[ks], bHr, aR[p], 0, 0, 0);
        aZ[p] = __builtin_amdgcn_mfma_f32_16x16x32_f16(aA[ks], bWz, aZ[p], 0, 0, 0);
        aZ[p] = __builtin_amdgcn_mfma_f32_16x16x32_f16(aH[ks], bHz, aZ[p], 0, 0, 0);
        aN[p] = __builtin_amdgcn_mfma_f32_16x16x32_f16(aA[ks], bWn, aN[p], 0, 0, 0);
        aHNa[p] = __builtin_amdgcn_mfma_f32_16x16x32_f16(aH[ks], bHn, aHNa[p], 0, 0, 0);
      }
    }
#pragma unroll
    for (int p = 0; p < 2; ++p)
      aHO[p] = __builtin_amdgcn_mfma_f32_16x16x32_f16(aH[half], idf[p], aHO[p], 0, 0, 0);
    // epilogue: lane (q,c) holds D[node = nb0 + q*4+r][dim = (half*2+p)*16+c]
#pragma unroll
    for (int p = 0; p < 2; ++p) {
      int d = (half * 2 + p) * 16 + c;
#pragma unroll
      for (int r = 0; r < 4; ++r) {
        int node = nb0 + q * 4 + r;
        if (node < N) {
          float rr = sigmoidf_(aR[p][r]);
          float zz = sigmoidf_(aZ[p][r]);
          float nn = tanhf_(aN[p][r] + rr * aHNa[p][r]);
          float out = nn + zz * (aHO[p][r] - nn);
          xh_out[(size_t)node * 64 + d] = (_Float16)out;
        }
      }
    }
  }
}

// ---------------- pooling (f16 input) ----------------
__global__ __launch_bounds__(256) void pool_kernel(const _Float16* __restrict__ xh,
                                                   const int* __restrict__ batch,
                                                   float* __restrict__ g, int N) {
  int wave = threadIdx.x >> 6, lane = threadIdx.x & 63;
  int n0 = blockIdx.x * 64 + wave * 16;
  if (n0 >= N) return;
  int end = n0 + 16;
  if (end > N) end = N;
  int cur = batch[n0];
  float acc = 0.f;
  for (int n = n0; n < end; ++n) {
    int b = batch[n];
    if (b != cur) {
      atomicAdd(&g[(size_t)cur * 64 + lane], acc);
      acc = 0.f;
      cur = b;
    }
    acc += (float)xh[(size_t)n * 64 + lane];
  }
  atomicAdd(&g[(size_t)cur * 64 + lane], acc);
}

// ---------------- final MLP ----------------
__global__ __launch_bounds__(256) void mlp_kernel(const float* __restrict__ g,
                                                  const float* __restrict__ w1,
                                                  const float* __restrict__ b1,
                                                  const float* __restrict__ w2,
                                                  const float* __restrict__ b2,
                                                  const float* __restrict__ w3,
                                                  const float* __restrict__ b3,
                                                  float* __restrict__ out, int G) {
  __shared__ float sG[64 * 64];
  __shared__ float sH1[64 * 32];
  __shared__ float sH2[64 * 16];
  int t = threadIdx.x;
  for (int i = t; i < G * 64; i += 256) sG[i] = g[i];
  __syncthreads();
  for (int o = t; o < G * 32; o += 256) {
    int gi = o >> 5, i = o & 31;
    float a = b1[i];
    for (int k = 0; k < 64; ++k) a += sG[gi * 64 + k] * w1[i * 64 + k];
    sH1[gi * 32 + i] = eluf_(a);
  }
  __syncthreads();
  for (int o = t; o < G * 16; o += 256) {
    int gi = o >> 4, i = o & 15;
    float a = b2[i];
    for (int k = 0; k < 32; ++k) a += sH1[gi * 32 + k] * w2[i * 32 + k];
    sH2[gi * 16 + i] = eluf_(a);
  }
  __syncthreads();
  for (int o = t; o < G; o += 256) {
    float a = b3[0];
    for (int k = 0; k < 16; ++k) a += sH2[o * 16 + k] * w3[k];
    out[o] = a;
  }
}

extern "C" void kernel_launch(void* const* d_in, const int* in_sizes, int n_in,
                              void* d_out, int out_size, void* d_ws, size_t ws_size,
                              hipStream_t stream) {
  const float* conv_w = (const float*)d_in[0];
  const float* w_ih = (const float*)d_in[1];
  const float* w_hh = (const float*)d_in[2];
  const float* b_ih = (const float*)d_in[3];
  const float* b_hh = (const float*)d_in[4];
  const float* fc1_w = (const float*)d_in[5];
  const float* fc1_b = (const float*)d_in[6];
  const float* fc2_w = (const float*)d_in[7];
  const float* fc2_b = (const float*)d_in[8];
  const float* fc3_w = (const float*)d_in[9];
  const float* fc3_b = (const float*)d_in[10];
  const int* ei = (const int*)d_in[11];
  const int* batch = (const int*)d_in[12];
  const int N = in_sizes[12];
  const int E = in_sizes[11] / 2;
  const int G = out_size;
  const int* src = ei;
  const int* dst = ei + E;
  const int nbk = (N + 1023) >> CBITS;
  const int tiles = (N + 63) / 64;
  const int Npad = tiles * 64;
  const int gruIter = tiles * 2;

  char* ws = (char*)d_ws;
  size_t off = 0;
  auto alloc = [&](size_t bytes) -> void* {
    void* p = ws + off;
    off += (bytes + 255) & ~(size_t)255;
    return p;
  };
  _Float16* xhA = (_Float16*)alloc((size_t)Npad * 64 * 2);
  _Float16* xhB = (_Float16*)alloc((size_t)Npad * 64 * 2);
  _Float16* aggh = (_Float16*)alloc((size_t)Npad * 64 * 2);
  _Float16* wcS = (_Float16*)alloc((size_t)5 * MATSZ * 2);
  _Float16* whhS = (_Float16*)alloc((size_t)5 * MATSZ * 2);
  float* h1 = (float*)alloc(64 * 4);
  float* l1u = (float*)alloc(192 * 4);
  float* l1c = (float*)alloc(256 * 4);
  float* gbuf = (float*)alloc((size_t)G * 64 * 4);
  int* offs = (int*)alloc((size_t)(N + 1) * 4);
  int* srcs = (int*)alloc((size_t)(E + 64) * 4);
  unsigned* pairs = (unsigned*)alloc((size_t)E * 4);
  int* bh = (int*)alloc(128 * 16 * 4);
  int* boffs = (int*)alloc(129 * 4);

  // --- CSR build ---
  hipMemsetAsync(bh, 0, 128 * 16 * 4, stream);
  bucket_hist_kernel<<<256, 256, 0, stream>>>(dst, bh, E);
  bucket_scan_kernel<<<1, 128, 0, stream>>>(bh, nbk, boffs, E);
  bucket_fill_kernel<<<(E + FCHUNK - 1) / FCHUNK, 256, 0, stream>>>(src, dst, bh, pairs, E);
  csr_build_kernel<<<nbk, 256, 0, stream>>>(pairs, boffs, offs, srcs, N, E);

  // --- weight prep: padded f16 images ---
  fuse_w_kernel<<<20, 256, 0, stream>>>(conv_w, w_ih, wcS);
  whh_prep_kernel<<<60, 256, 0, stream>>>(w_hh, whhS);

  // --- layers 0+1 closed form: h2[v] = F(deg[v]) written straight into xhA ---
  h1_kernel<<<1, 64, 0, stream>>>(b_ih, b_hh, h1);
  l1u_kernel<<<1, 256, 0, stream>>>(wcS + MATSZ, whhS + MATSZ, h1,
                                    b_ih + 192, b_hh + 192, l1u, l1c);
  l1_elem_kernel<<<(Npad * 32 + 255) / 256, 256, 0, stream>>>(offs, h1, l1u, l1c, xhA,
                                                              N, Npad * 32);

  // layers 2-4: agg + MFMA GRU, ping-pong A->B->A->B
  _Float16* cur = xhA;
  _Float16* nxt = xhB;
  for (int l = 2; l < 5; ++l) {
    agg_kernel<<<(N + 3) / 4, 256, 0, stream>>>(cur, offs, srcs, aggh, N);
    gru_kernel<<<768, 256, 0, stream>>>(aggh, cur, nxt, wcS + (size_t)l * MATSZ,
                                        whhS + (size_t)l * MATSZ, b_ih + (size_t)l * 192,
                                        b_hh + (size_t)l * 192, N, gruIter);
    _Float16* tmp = cur; cur = nxt; nxt = tmp;
  }

  hipMemsetAsync(gbuf, 0, (size_t)G * 64 * 4, stream);
  pool_kernel<<<(N + 63) / 64, 256, 0, stream>>>(cur, batch, gbuf, N);
  mlp_kernel<<<1, 256, 0, stream>>>(gbuf, fc1_w, fc1_b, fc2_w, fc2_b, fc3_w, fc3_b,
                                    (float*)d_out, G);
}